// Round 6
// baseline (4119.513 us; speedup 1.0000x reference)
//
#include <hip/hip_runtime.h>

namespace {

constexpr int NP   = 19712;   // padded tokens (Nystrom)
constexpr int NT   = 19601;   // tokens incl cls
constexpr int NPIX = 19600;   // feature tokens (140x140)
constexpr int HD   = 512;     // hidden dim
constexpr int ID   = 1024;    // input dim
constexpr int NH   = 8;       // heads
constexpr int DH   = 8;       // dim per head
constexpr int NL   = 256;     // landmarks
constexpr int PADR = 111;     // left zero-pad rows
constexpr int SIDE = 140;
constexpr int CCH  = 128;     // ppeg channel chunk
constexpr int PW   = 148;     // padded image row stride (floats)

typedef __attribute__((ext_vector_type(8))) short bf16x8;
typedef __attribute__((ext_vector_type(4))) float f32x4;

#define F4MAD(a, s, v) { (a).x += (s)*(v).x; (a).y += (s)*(v).y; (a).z += (s)*(v).z; (a).w += (s)*(v).w; }
#define F4SCALE(a, s)  { (a).x *= (s); (a).y *= (s); (a).z *= (s); (a).w *= (s); }

__device__ inline short f2bf(float f) {
    union { float f; unsigned u; } v; v.f = f;
    unsigned r = v.u + 0x7fffu + ((v.u >> 16) & 1u);
    return (short)(r >> 16);
}

// ------------------------------------------------------------------
// cast X fp32 -> bf16 elementwise (same [m][k] layout)
// ------------------------------------------------------------------
__global__ void castX(const float* __restrict__ src, short* __restrict__ dst)
{
    size_t c = (size_t)blockIdx.x * 256 + threadIdx.x;   // chunk of 8
    const float4 x0 = *(const float4*)&src[c * 8];
    const float4 x1 = *(const float4*)&src[c * 8 + 4];
    bf16x8 p;
    p[0] = f2bf(x0.x); p[1] = f2bf(x0.y); p[2] = f2bf(x0.z); p[3] = f2bf(x0.w);
    p[4] = f2bf(x1.x); p[5] = f2bf(x1.y); p[6] = f2bf(x1.z); p[7] = f2bf(x1.w);
    *(bf16x8*)&dst[c * 8] = p;
}

// ------------------------------------------------------------------
// cast+transpose: dst[c][r] = bf16(src[r][c]); grid (C/32, R/32)
// ------------------------------------------------------------------
__global__ void castT(const float* __restrict__ src, short* __restrict__ dst, int R, int C)
{
    __shared__ float t[32][33];
    const int tx = threadIdx.x & 31, ty = threadIdx.x >> 5;
    const int c0 = blockIdx.x * 32, r0 = blockIdx.y * 32;
    #pragma unroll
    for (int j = 0; j < 4; ++j)
        t[ty + 8 * j][tx] = src[(size_t)(r0 + ty + 8 * j) * C + c0 + tx];
    __syncthreads();
    #pragma unroll
    for (int j = 0; j < 4; ++j)
        dst[(size_t)(c0 + ty + 8 * j) * R + r0 + tx] = f2bf(t[tx][ty + 8 * j]);
}

// ------------------------------------------------------------------
// fc1 MFMA: out[1+m][n] = gelu(Xb[m] @ W[:,n] + b[n]); M=19600 K=1024 N=512
// Xb bf16 [m][k], Wt bf16 [n][k]. 128x64 tile, 4 waves 2x2 (64x32 each).
// grid (154, 8)
// ------------------------------------------------------------------
__global__ __launch_bounds__(256) void gemm_fc1(const short* __restrict__ Xb,
                                                const short* __restrict__ Wt,
                                                const float* __restrict__ bias,
                                                float* __restrict__ out)
{
    __shared__ __align__(16) short As[128 * 40];
    __shared__ __align__(16) short Bs[64 * 40];
    const int tid  = threadIdx.x;
    const int row0 = blockIdx.x * 128;
    const int col0 = blockIdx.y * 64;
    const int wave = tid >> 6, lane = tid & 63;
    const int quad = lane >> 4, l16 = lane & 15;
    const int m_off = (wave >> 1) * 64, n_off = (wave & 1) * 32;
    f32x4 acc[4][2] = {};
    for (int k0 = 0; k0 < ID; k0 += 32) {
        #pragma unroll
        for (int seg = 0; seg < 2; ++seg) {
            int lin = tid + 256 * seg;
            int row = lin >> 2, kc = (lin & 3) * 8;
            int gr = row0 + row;
            bf16x8 pa = {};
            if (gr < NPIX) pa = *(const bf16x8*)&Xb[(size_t)gr * ID + k0 + kc];
            *(bf16x8*)&As[row * 40 + kc] = pa;
        }
        {
            int nrow = tid >> 2, kc = (tid & 3) * 8;
            *(bf16x8*)&Bs[nrow * 40 + kc] =
                *(const bf16x8*)&Wt[(size_t)(col0 + nrow) * ID + k0 + kc];
        }
        __syncthreads();
        bf16x8 af[4], bf[2];
        #pragma unroll
        for (int i = 0; i < 4; ++i)
            af[i] = *(const bf16x8*)&As[(m_off + i * 16 + l16) * 40 + quad * 8];
        #pragma unroll
        for (int i = 0; i < 2; ++i)
            bf[i] = *(const bf16x8*)&Bs[(n_off + i * 16 + l16) * 40 + quad * 8];
        #pragma unroll
        for (int mi = 0; mi < 4; ++mi)
            #pragma unroll
            for (int ni = 0; ni < 2; ++ni)
                acc[mi][ni] = __builtin_amdgcn_mfma_f32_16x16x32_bf16(af[mi], bf[ni], acc[mi][ni], 0, 0, 0);
        __syncthreads();
    }
    #pragma unroll
    for (int mi = 0; mi < 4; ++mi) {
        #pragma unroll
        for (int r = 0; r < 4; ++r) {
            int gr = row0 + m_off + mi * 16 + quad * 4 + r;
            if (gr >= NPIX) continue;
            #pragma unroll
            for (int ni = 0; ni < 2; ++ni) {
                int gc = col0 + n_off + ni * 16 + l16;
                float v = acc[mi][ni][r] + bias[gc];
                v = 0.5f * v * (1.f + erff(v * 0.70710678118654752f));
                out[(size_t)(gr + 1) * HD + gc] = v;
            }
        }
    }
}

// ------------------------------------------------------------------
// qkv MFMA: xpB(19712x512 bf16) @ Wt(192x512 bf16) -> qh/kh/vh fp32
// 64x64 tile, 4 waves 2x2 (32x32 each). grid (308, 3)
// ------------------------------------------------------------------
__global__ __launch_bounds__(256) void gemm_qkv(const short* __restrict__ xpB,
                                                const short* __restrict__ Wt,
                                                float* __restrict__ qh,
                                                float* __restrict__ kh,
                                                float* __restrict__ vh)
{
    __shared__ __align__(16) short As[64 * 40];
    __shared__ __align__(16) short Bs[64 * 40];
    const int tid  = threadIdx.x;
    const int row0 = blockIdx.x * 64;
    const int col0 = blockIdx.y * 64;
    const int wave = tid >> 6, lane = tid & 63;
    const int quad = lane >> 4, l16 = lane & 15;
    const int m_off = (wave >> 1) * 32, n_off = (wave & 1) * 32;
    f32x4 acc[2][2] = {};
    for (int k0 = 0; k0 < HD; k0 += 32) {
        {
            int row = tid >> 2, kc = (tid & 3) * 8;
            *(bf16x8*)&As[row * 40 + kc] =
                *(const bf16x8*)&xpB[(size_t)(row0 + row) * HD + k0 + kc];
            *(bf16x8*)&Bs[row * 40 + kc] =
                *(const bf16x8*)&Wt[(size_t)(col0 + row) * HD + k0 + kc];
        }
        __syncthreads();
        bf16x8 af[2], bf[2];
        #pragma unroll
        for (int i = 0; i < 2; ++i) {
            af[i] = *(const bf16x8*)&As[(m_off + i * 16 + l16) * 40 + quad * 8];
            bf[i] = *(const bf16x8*)&Bs[(n_off + i * 16 + l16) * 40 + quad * 8];
        }
        #pragma unroll
        for (int mi = 0; mi < 2; ++mi)
            #pragma unroll
            for (int ni = 0; ni < 2; ++ni)
                acc[mi][ni] = __builtin_amdgcn_mfma_f32_16x16x32_bf16(af[mi], bf[ni], acc[mi][ni], 0, 0, 0);
        __syncthreads();
    }
    const int which = blockIdx.y;
    float* dst = (which == 0) ? qh : (which == 1) ? kh : vh;
    const float scale = (which == 0) ? 0.35355339059327373f : 1.f;
    #pragma unroll
    for (int mi = 0; mi < 2; ++mi) {
        #pragma unroll
        for (int r = 0; r < 4; ++r) {
            int gr = row0 + m_off + mi * 16 + quad * 4 + r;
            #pragma unroll
            for (int ni = 0; ni < 2; ++ni) {
                int n = n_off + ni * 16 + l16;     // 0..63 local
                int hh = n >> 3, d = n & 7;
                dst[((size_t)hh * NP + gr) * DH + d] = acc[mi][ni][r] * scale;
            }
        }
    }
}

__global__ void cls_init(const float* __restrict__ cls, float* __restrict__ h)
{
    int t = blockIdx.x * 256 + threadIdx.x;
    if (t < HD) h[t] = cls[t];
}

__global__ void copy512(const float* __restrict__ src, float* __restrict__ dst)
{
    dst[threadIdx.x] = src[threadIdx.x];
}

// ------------------------------------------------------------------
// layernorm rows of h into xp (bf16!), first 111 rows zero
// ------------------------------------------------------------------
__global__ void ln_pad(const float* __restrict__ h, const float* __restrict__ g,
                       const float* __restrict__ b, short* __restrict__ xp)
{
    const int row = blockIdx.x;
    const int tid = threadIdx.x;
    short* dst = xp + (size_t)row * HD;
    if (row < PADR) { dst[tid] = 0; dst[tid + 256] = 0; return; }
    const float* src = h + (size_t)(row - PADR) * HD;
    float v0 = src[tid], v1 = src[tid + 256];
    __shared__ float red[256];
    red[tid] = v0 + v1;
    __syncthreads();
    for (int off = 128; off > 0; off >>= 1) {
        if (tid < off) red[tid] += red[tid + off];
        __syncthreads();
    }
    float mu = red[0] * (1.f / HD);
    __syncthreads();
    float d0 = v0 - mu, d1 = v1 - mu;
    red[tid] = d0 * d0 + d1 * d1;
    __syncthreads();
    for (int off = 128; off > 0; off >>= 1) {
        if (tid < off) red[tid] += red[tid + off];
        __syncthreads();
    }
    float inv = rsqrtf(red[0] * (1.f / HD) + 1e-5f);
    dst[tid]       = f2bf(d0 * inv * g[tid] + b[tid]);
    dst[tid + 256] = f2bf(d1 * inv * g[tid + 256] + b[tid + 256]);
}

// ------------------------------------------------------------------
// landmark means (qh/kh fp32 -> ql/kl fp32)
// ------------------------------------------------------------------
__global__ void landmarks(const float* __restrict__ qh, const float* __restrict__ kh,
                          float* __restrict__ ql, float* __restrict__ kl)
{
    int idx = blockIdx.x * 256 + threadIdx.x;
    int sel = idx >> 14;
    int rem = idx & 16383;
    int h = rem >> 11;
    int i = (rem >> 3) & 255;
    int d = rem & 7;
    const float* src = sel ? kh : qh;
    size_t base = ((size_t)h * NP + (size_t)i * 77) * DH + d;
    float s = 0.f;
    for (int j = 0; j < 77; ++j) s += src[base + (size_t)j * DH];
    (sel ? kl : ql)[((size_t)h * NL + i) * DH + d] = s * (1.f / 77.f);
}

// ------------------------------------------------------------------
// attn2 = softmax(q_l @ k_l^T)
// ------------------------------------------------------------------
__global__ void attn2_softmax(const float* __restrict__ ql, const float* __restrict__ kl,
                              float* __restrict__ a)
{
    const int i = blockIdx.x, h = blockIdx.y, j = threadIdx.x;
    __shared__ float sq[8];
    __shared__ float red[256];
    if (j < 8) sq[j] = ql[((size_t)h * NL + i) * DH + j];
    __syncthreads();
    const float* kr = kl + ((size_t)h * NL + j) * DH;
    float s = 0.f;
    #pragma unroll
    for (int d = 0; d < 8; ++d) s += sq[d] * kr[d];
    red[j] = s;
    __syncthreads();
    for (int off = 128; off > 0; off >>= 1) {
        if (j < off) red[j] = fmaxf(red[j], red[j + off]);
        __syncthreads();
    }
    float mx = red[0];
    __syncthreads();
    float e = __expf(s - mx);
    red[j] = e;
    __syncthreads();
    for (int off = 128; off > 0; off >>= 1) {
        if (j < off) red[j] += red[j + off];
        __syncthreads();
    }
    a[((size_t)h * NL + i) * NL + j] = e / red[0];
}

// ------------------------------------------------------------------
// cooperative pinv: norms + z0 + 6 Newton iterations in ONE kernel.
// 256 blocks (1/CU), software barriers (agent scope). 32 blocks/head.
// barbuf layout (uints): [0] gcnt, [16] ggen, [32+h*32] hcnt, [48+h*32] hgen,
//                        [1024] rowmax bits, [1025] colmax bits
// ------------------------------------------------------------------
__device__ __forceinline__ void swbar(unsigned* cnt, unsigned* gen, unsigned n)
{
    __threadfence();
    __syncthreads();
    if (threadIdx.x == 0) {
        unsigned g = __hip_atomic_load(gen, __ATOMIC_RELAXED, __HIP_MEMORY_SCOPE_AGENT);
        unsigned a = __hip_atomic_fetch_add(cnt, 1u, __ATOMIC_ACQ_REL, __HIP_MEMORY_SCOPE_AGENT);
        if (a == n - 1) {
            __hip_atomic_store(cnt, 0u, __ATOMIC_RELAXED, __HIP_MEMORY_SCOPE_AGENT);
            __hip_atomic_fetch_add(gen, 1u, __ATOMIC_RELEASE, __HIP_MEMORY_SCOPE_AGENT);
        } else {
            while (__hip_atomic_load(gen, __ATOMIC_ACQUIRE, __HIP_MEMORY_SCOPE_AGENT) == g)
                __builtin_amdgcn_s_sleep(8);
        }
    }
    __syncthreads();
    __threadfence();
}

__device__ void mm_phase(const float* __restrict__ Ah, const float* __restrict__ Bh,
                         float* __restrict__ Dh, float alpha, float beta,
                         int row0, int col0, int tid,
                         float (&As)[16][36], float (&Bs)[16][68])
{
    const int tx = tid & 15, ty = tid >> 4;
    float acc[2][4] = {};
    const int ar = tid >> 3;
    const int ak = (tid & 7) * 2;
    const int bk = tid >> 4;
    const int bj = (tid & 15) * 4;
    for (int k0 = 0; k0 < NL; k0 += 16) {
        float2 av = *(const float2*)&Ah[(size_t)(row0 + ar) * NL + k0 + ak];
        As[ak][ar] = av.x; As[ak + 1][ar] = av.y;
        *(float4*)&Bs[bk][bj] = *(const float4*)&Bh[(size_t)(k0 + bk) * NL + col0 + bj];
        __syncthreads();
        #pragma unroll
        for (int k = 0; k < 16; ++k) {
            float2 a = *(const float2*)&As[k][ty * 2];
            float4 b = *(const float4*)&Bs[k][tx * 4];
            acc[0][0] += a.x * b.x; acc[0][1] += a.x * b.y; acc[0][2] += a.x * b.z; acc[0][3] += a.x * b.w;
            acc[1][0] += a.y * b.x; acc[1][1] += a.y * b.y; acc[1][2] += a.y * b.z; acc[1][3] += a.y * b.w;
        }
        __syncthreads();
    }
    #pragma unroll
    for (int r = 0; r < 2; ++r) {
        int gr = row0 + ty * 2 + r;
        #pragma unroll
        for (int c = 0; c < 4; ++c) {
            int gc = col0 + tx * 4 + c;
            Dh[(size_t)gr * NL + gc] = alpha * acc[r][c] + beta * Ah[(size_t)gr * NL + gc];
        }
    }
}

__global__ __launch_bounds__(256, 1) void pinv_all(const float* __restrict__ a,
                                                   float* __restrict__ z0b,
                                                   float* __restrict__ z1b,
                                                   float* __restrict__ Yb,
                                                   float* __restrict__ Tb,
                                                   float* __restrict__ Ub,
                                                   unsigned* __restrict__ bb)
{
    __shared__ float As[16][36];
    __shared__ float Bs[16][68];
    __shared__ float rred[8], cred[8];
    const int tid = threadIdx.x;
    const int h = blockIdx.x >> 5;
    const int seg = blockIdx.x & 31;
    const size_t hoff = (size_t)h * NL * NL;
    const float* ah = a + hoff;

    // ---- phase: norms (global max of rowsums / colsums) ----
    {
        int r = tid >> 5;       // 0..7
        int ch = tid & 31;      // 0..31
        float rs = 0.f;
        const float* rp = ah + (size_t)(seg * 8 + r) * NL + ch * 8;
        #pragma unroll
        for (int j = 0; j < 8; ++j) rs += fabsf(rp[j]);
        #pragma unroll
        for (int off = 16; off > 0; off >>= 1) rs += __shfl_down(rs, off, 32);
        float cs = 0.f;
        const float* cp = ah + (size_t)(ch * 8) * NL + seg * 8 + r;
        #pragma unroll
        for (int j = 0; j < 8; ++j) cs += fabsf(cp[(size_t)j * NL]);
        #pragma unroll
        for (int off = 16; off > 0; off >>= 1) cs += __shfl_down(cs, off, 32);
        if (ch == 0) { rred[r] = rs; cred[r] = cs; }
        __syncthreads();
        if (tid == 0) {
            float rm = rred[0], cm = cred[0];
            #pragma unroll
            for (int j = 1; j < 8; ++j) { rm = fmaxf(rm, rred[j]); cm = fmaxf(cm, cred[j]); }
            atomicMax(&bb[1024], __float_as_uint(rm));
            atomicMax(&bb[1025], __float_as_uint(cm));
        }
    }
    swbar(&bb[0], &bb[16], 256);
    const float inv = 1.f / (__uint_as_float(bb[1024]) * __uint_as_float(bb[1025]));

    // ---- phase: z0 = a^T * inv (rows seg*8..+8 of head h) ----
    for (int idx = tid; idx < 2048; idx += 256) {
        int i = seg * 8 + (idx >> 8);
        int j = idx & 255;
        z0b[hoff + (size_t)i * NL + j] = ah[(size_t)j * NL + i] * inv;
    }

    unsigned* hcnt = &bb[32 + h * 32];
    unsigned* hgen = &bb[48 + h * 32];
    swbar(hcnt, hgen, 32);

    // ---- 6 Newton-Schulz iterations ----
    const int row0 = (seg >> 2) * 32;
    const int col0 = (seg & 3) * 64;
    float* zc = z0b + hoff;
    float* zn = z1b + hoff;
    float* Y  = Yb + hoff;
    float* T  = Tb + hoff;
    float* U  = Ub + hoff;
    for (int it = 0; it < 6; ++it) {
        mm_phase(ah, zc, Y, 1.f, 0.f, row0, col0, tid, As, Bs);
        swbar(hcnt, hgen, 32);
        mm_phase(Y, Y, T, -1.f, 7.f, row0, col0, tid, As, Bs);
        swbar(hcnt, hgen, 32);
        mm_phase(Y, T, U, -1.f, 15.f, row0, col0, tid, As, Bs);
        swbar(hcnt, hgen, 32);
        mm_phase(zc, U, zn, -0.25f, 3.25f, row0, col0, tid, As, Bs);
        swbar(hcnt, hgen, 32);
        float* tmp = zc; zc = zn; zn = tmp;
    }
    // 6 swaps -> final z in z0b
}

__global__ void pinv_init(unsigned* __restrict__ bb)
{
    bb[blockIdx.x * 256 + threadIdx.x] = 0u;
}

// ------------------------------------------------------------------
// attn3 @ v: 4 landmarks/block, branchless online softmax, shfl merge
// ------------------------------------------------------------------
__global__ void attn3v(const float* __restrict__ kh, const float* __restrict__ vh,
                       const float* __restrict__ ql, float* __restrict__ wbuf)
{
    const int i0 = blockIdx.x * 4, h = blockIdx.y, tid = threadIdx.x;
    __shared__ float sq[4][8];
    __shared__ float wred[4][4][10];
    if (tid < 32) sq[tid >> 3][tid & 7] = ql[((size_t)h * NL + i0 + (tid >> 3)) * DH + (tid & 7)];
    __syncthreads();
    float q[4][8];
    #pragma unroll
    for (int li = 0; li < 4; ++li)
        #pragma unroll
        for (int d = 0; d < 8; ++d) q[li][d] = sq[li][d];
    const float* kb = kh + (size_t)h * NP * DH;
    const float* vb = vh + (size_t)h * NP * DH;
    float m[4] = {-1e30f, -1e30f, -1e30f, -1e30f};
    float den[4] = {};
    float acc[4][8] = {};
    for (int t = tid; t < NP; t += 256) {
        const float4 k0 = *(const float4*)&kb[(size_t)t * 8];
        const float4 k1 = *(const float4*)&kb[(size_t)t * 8 + 4];
        const float4 v0 = *(const float4*)&vb[(size_t)t * 8];
        const float4 v1 = *(const float4*)&vb[(size_t)t * 8 + 4];
        float vv[8] = {v0.x, v0.y, v0.z, v0.w, v1.x, v1.y, v1.z, v1.w};
        float kk[8] = {k0.x, k0.y, k0.z, k0.w, k1.x, k1.y, k1.z, k1.w};
        #pragma unroll
        for (int li = 0; li < 4; ++li) {
            float s = 0.f;
            #pragma unroll
            for (int d = 0; d < 8; ++d) s += q[li][d] * kk[d];
            float nm = fmaxf(m[li], s);
            float sc = __expf(m[li] - nm);
            float e  = __expf(s - nm);
            m[li] = nm;
            den[li] = den[li] * sc + e;
            #pragma unroll
            for (int d = 0; d < 8; ++d) acc[li][d] = acc[li][d] * sc + e * vv[d];
        }
    }
    #pragma unroll
    for (int off = 1; off < 64; off <<= 1) {
        #pragma unroll
        for (int li = 0; li < 4; ++li) {
            float mo = __shfl_xor(m[li], off);
            float dn = __shfl_xor(den[li], off);
            float ao[8];
            #pragma unroll
            for (int d = 0; d < 8; ++d) ao[d] = __shfl_xor(acc[li][d], off);
            float nm = fmaxf(m[li], mo);
            float s1 = __expf(m[li] - nm), s2 = __expf(mo - nm);
            den[li] = den[li] * s1 + dn * s2;
            #pragma unroll
            for (int d = 0; d < 8; ++d) acc[li][d] = acc[li][d] * s1 + ao[d] * s2;
            m[li] = nm;
        }
    }
    const int wave = tid >> 6, lane = tid & 63;
    if (lane == 0) {
        #pragma unroll
        for (int li = 0; li < 4; ++li) {
            wred[wave][li][0] = m[li];
            wred[wave][li][1] = den[li];
            #pragma unroll
            for (int d = 0; d < 8; ++d) wred[wave][li][2 + d] = acc[li][d];
        }
    }
    __syncthreads();
    if (tid < 4) {
        const int li = tid;
        float M = wred[0][li][0], D_ = wred[0][li][1];
        float A[8];
        #pragma unroll
        for (int d = 0; d < 8; ++d) A[d] = wred[0][li][2 + d];
        #pragma unroll
        for (int w = 1; w < 4; ++w) {
            float mo = wred[w][li][0], dn = wred[w][li][1];
            float nm = fmaxf(M, mo);
            float s1 = __expf(M - nm), s2 = __expf(mo - nm);
            D_ = D_ * s1 + dn * s2;
            #pragma unroll
            for (int d = 0; d < 8; ++d) A[d] = A[d] * s1 + wred[w][li][2 + d] * s2;
            M = nm;
        }
        #pragma unroll
        for (int d = 0; d < 8; ++d)
            wbuf[((size_t)h * NL + i0 + li) * DH + d] = A[d] / D_;
    }
}

// ------------------------------------------------------------------
// zw[h][i][d] = sum_j z[h][i][j] * w[h][j][d]
// ------------------------------------------------------------------
__global__ void zw_mul(const float* __restrict__ z, const float* __restrict__ w,
                       float* __restrict__ zw)
{
    int idx = blockIdx.x * 256 + threadIdx.x;
    int h = idx >> 11;
    int rem = idx & 2047;
    int i = rem >> 3, d = rem & 7;
    const float* zr = z + ((size_t)h * NL + i) * NL;
    const float* wb = w + (size_t)h * NL * DH + d;
    float s = 0.f;
    for (int j = 0; j < NL; ++j) s += zr[j] * wb[(size_t)j * DH];
    zw[idx] = s;
}

// ------------------------------------------------------------------
// attn1 fused + dwconv33(v), branchless online softmax
// ------------------------------------------------------------------
__global__ void attn1_conv(const float* __restrict__ qh, const float* __restrict__ vh,
                           const float* __restrict__ klg, const float* __restrict__ zwg,
                           const float* __restrict__ rw, float* __restrict__ aout)
{
    const int h = blockIdx.y;
    __shared__ __align__(16) float kl[NL * DH];
    __shared__ __align__(16) float zw[NL * DH];
    const int tid = threadIdx.x;
    for (int q = tid; q < NL * DH; q += 256) {
        kl[q] = klg[(size_t)h * NL * DH + q];
        zw[q] = zwg[(size_t)h * NL * DH + q];
    }
    __syncthreads();
    const int r = blockIdx.x * 256 + tid;
    if (r >= NT) return;
    const int t = r + PADR;
    const float* qp = qh + ((size_t)h * NP + t) * DH;
    float4 q0 = *(const float4*)qp;
    float4 q1 = *(const float4*)(qp + 4);
    float m = -1e30f, den = 0.f;
    float4 acc0 = make_float4(0.f, 0.f, 0.f, 0.f);
    float4 acc1 = make_float4(0.f, 0.f, 0.f, 0.f);
    for (int i = 0; i < NL; ++i) {
        float4 k0 = *(const float4*)&kl[i * 8];
        float4 k1 = *(const float4*)&kl[i * 8 + 4];
        float s = q0.x * k0.x + q0.y * k0.y + q0.z * k0.z + q0.w * k0.w
                + q1.x * k1.x + q1.y * k1.y + q1.z * k1.z + q1.w * k1.w;
        float nm = fmaxf(m, s);
        float sc = __expf(m - nm);
        float e  = __expf(s - nm);
        m = nm;
        den = den * sc + e;
        float4 z0 = *(const float4*)&zw[i * 8];
        float4 z1 = *(const float4*)&zw[i * 8 + 4];
        acc0.x = acc0.x * sc + e * z0.x; acc0.y = acc0.y * sc + e * z0.y;
        acc0.z = acc0.z * sc + e * z0.z; acc0.w = acc0.w * sc + e * z0.w;
        acc1.x = acc1.x * sc + e * z1.x; acc1.y = acc1.y * sc + e * z1.y;
        acc1.z = acc1.z * sc + e * z1.z; acc1.w = acc1.w * sc + e * z1.w;
    }
    float inv = 1.f / den;
    F4SCALE(acc0, inv); F4SCALE(acc1, inv);
    const float* vb = vh + (size_t)h * NP * DH;
    #pragma unroll
    for (int j = 0; j < 33; ++j) {
        int tp = t - 16 + j;
        if (tp >= NP) continue;
        float wv = rw[h * 33 + j];
        float4 v0 = *(const float4*)&vb[(size_t)tp * 8];
        float4 v1 = *(const float4*)&vb[(size_t)tp * 8 + 4];
        F4MAD(acc0, wv, v0); F4MAD(acc1, wv, v1);
    }
    float* op = aout + (size_t)r * 64 + h * 8;
    *(float4*)op = acc0;
    *(float4*)(op + 4) = acc1;
}

// ------------------------------------------------------------------
// out-proj + residual: 16 rows/block
// ------------------------------------------------------------------
__global__ void outproj(const float* __restrict__ aout, const float* __restrict__ W,
                        const float* __restrict__ bias, float* __restrict__ h)
{
    const int r0 = blockIdx.x * 16;
    const int tid = threadIdx.x;   // 512
    __shared__ float ao[16][64];
    #pragma unroll
    for (int s = 0; s < 2; ++s) {
        int idx = tid + s * 512;
        int rr = idx >> 6, kk = idx & 63;
        int gr = r0 + rr;
        ao[rr][kk] = (gr < NT) ? aout[(size_t)gr * 64 + kk] : 0.f;
    }
    __syncthreads();
    float acc[16] = {};
    for (int k = 0; k < 64; ++k) {
        float wv = W[(size_t)k * HD + tid];
        #pragma unroll
        for (int r = 0; r < 16; ++r) acc[r] += ao[r][k] * wv;
    }
    float bv = bias[tid];
    #pragma unroll
    for (int r = 0; r < 16; ++r) {
        int gr = r0 + r;
        if (gr < NT) h[(size_t)gr * HD + tid] += acc[r] + bv;
    }
}

// ------------------------------------------------------------------
// PPEG
// ------------------------------------------------------------------
__global__ void ppeg_wprep(const float* __restrict__ w7, const float* __restrict__ b7,
                           const float* __restrict__ w5, const float* __restrict__ b5,
                           const float* __restrict__ w3, const float* __restrict__ b3,
                           float* __restrict__ wc, float* __restrict__ bsum)
{
    int idx = blockIdx.x * 256 + threadIdx.x;
    if (idx < HD * 49) {
        int c = idx / 49, t = idx - c * 49;
        int dy = t / 7 - 3, dx = t % 7 - 3;
        float v = w7[idx];
        if (dy >= -2 && dy <= 2 && dx >= -2 && dx <= 2) v += w5[c * 25 + (dy + 2) * 5 + (dx + 2)];
        if (dy >= -1 && dy <= 1 && dx >= -1 && dx <= 1) v += w3[c * 9 + (dy + 1) * 3 + (dx + 1)];
        if (t == 24) v += 1.f;
        wc[idx] = v;
    } else if (idx < HD * 49 + HD) {
        int c = idx - HD * 49;
        bsum[c] = b7[c] + b5[c] + b3[c];
    }
}

__global__ void ppeg_t1(const float* __restrict__ hin, float* __restrict__ plan, int ch0)
{
    __shared__ float tile[32][33];
    const int tx = threadIdx.x & 31, ty = threadIdx.x >> 5;
    const int p0 = blockIdx.x * 32;
    const int c0 = ch0 + blockIdx.y * 32;
    #pragma unroll
    for (int j = 0; j < 4; ++j) {
        int p = p0 + ty + j * 8;
        tile[ty + j * 8][tx] = (p < NPIX) ? hin[(size_t)(1 + p) * HD + c0 + tx] : 0.f;
    }
    __syncthreads();
    #pragma unroll
    for (int j = 0; j < 4; ++j) {
        int p = p0 + tx;
        int cc = ty + j * 8;
        if (p < NPIX) plan[(size_t)(blockIdx.y * 32 + cc) * NPIX + p] = tile[tx][cc];
    }
}

__global__ __launch_bounds__(256) void ppeg_conv(const float* __restrict__ plan,
                                                 const float* __restrict__ wc,
                                                 float* __restrict__ plan2, int ch0)
{
    __shared__ __align__(16) float img[41 * PW];
    const int tid = threadIdx.x;
    const int cl = blockIdx.x;
    const int yq = blockIdx.y;
    for (int i = tid; i < 41 * PW; i += 256) img[i] = 0.f;
    __syncthreads();
    const float* src = plan + (size_t)cl * NPIX;
    for (int i = tid; i < 41 * SIDE; i += 256) {
        int ly = i / SIDE, x = i - ly * SIDE;
        int y = yq * 35 - 3 + ly;
        if (y >= 0 && y < SIDE) img[ly * PW + x + 3] = src[y * SIDE + x];
    }
    const float* w = wc + (size_t)(ch0 + cl) * 49;
    float wr[49];
    #pragma unroll
    for (int t = 0; t < 49; ++t) wr[t] = w[t];
    __syncthreads();
    float* dst = plan2 + (size_t)cl * NPIX;
    for (int g = tid; g < 35 * 35; g += 256) {
        int yl = g / 35, x0 = (g - yl * 35) * 4;
        float acc0 = 0.f, acc1 = 0.f, acc2 = 0.f, acc3 = 0.f;
        #pragma unroll
        for (int a = 0; a < 7; ++a) {
            const float* row = &img[(yl + a) * PW + x0];
            float4 A = *(const float4*)(row);
            float4 B = *(const float4*)(row + 4);
            float4 C = *(const float4*)(row + 8);
            float e0 = A.x, e1 = A.y, e2 = A.z, e3 = A.w;
            float e4 = B.x, e5 = B.y, e6 = B.z, e7 = B.w;
            float e8 = C.x, e9 = C.y;
            const float w0 = wr[a*7+0], w1 = wr[a*7+1], w2 = wr[a*7+2], w3v = wr[a*7+3];
            const float w4 = wr[a*7+4], w5v = wr[a*7+5], w6 = wr[a*7+6];
            acc0 += w0*e0 + w1*e1 + w2*e2 + w3v*e3 + w4*e4 + w5v*e5 + w6*e6;
            acc1 += w0*e1 + w1*e2 + w2*e3 + w3v*e4 + w4*e5 + w5v*e6 + w6*e7;
            acc2 += w0*e2 + w1*e3 + w2*e4 + w3v*e5 + w4*e6 + w5v*e7 + w6*e8;
            acc3 += w0*e3 + w1*e4 + w2*e5 + w3v*e6 + w4*e7 + w5v*e8 + w6*e9;
        }
        *(float4*)&dst[(yq * 35 + yl) * SIDE + x0] = make_float4(acc0, acc1, acc2, acc3);
    }
}

__global__ void ppeg_t2(const float* __restrict__ plan2, const float* __restrict__ bsum,
                        float* __restrict__ hout, int ch0)
{
    __shared__ float tile[32][33];
    const int tx = threadIdx.x & 31, ty = threadIdx.x >> 5;
    const int p0 = blockIdx.x * 32;
    #pragma unroll
    for (int j = 0; j < 4; ++j) {
        int p = p0 + tx;
        int cc = ty + j * 8;
        tile[tx][cc] = (p < NPIX) ? plan2[(size_t)(blockIdx.y * 32 + cc) * NPIX + p] : 0.f;
    }
    __syncthreads();
    const int c0 = ch0 + blockIdx.y * 32;
    float bv = bsum[c0 + tx];
    #pragma unroll
    for (int j = 0; j < 4; ++j) {
        int p = p0 + ty + j * 8;
        if (p < NPIX) hout[(size_t)(1 + p) * HD + c0 + tx] = tile[ty + j * 8][tx] + bv;
    }
}

// ------------------------------------------------------------------
// final layernorm of row 0
// ------------------------------------------------------------------
__global__ void final_ln(const float* __restrict__ h, const float* __restrict__ g,
                         const float* __restrict__ b, float* __restrict__ out)
{
    const int tid = threadIdx.x;
    float v0 = h[tid], v1 = h[tid + 256];
    __shared__ float red[256];
    red[tid] = v0 + v1;
    __syncthreads();
    for (int off = 128; off > 0; off >>= 1) {
        if (tid < off) red[tid] += red[tid + off];
        __syncthreads();
    }
    float mu = red[0] * (1.f / HD);
    __syncthreads();
    float d0 = v0 - mu, d1 = v1 - mu;
    red[tid] = d0 * d0 + d1 * d1;
    __syncthreads();
    for (int off = 128; off > 0; off >>= 1) {
        if (tid < off) red[tid] += red[tid + off];
        __syncthreads();
    }
    float inv = rsqrtf(red[0] * (1.f / HD) + 1e-5f);
    out[tid]       = d0 * inv * g[tid] + b[tid];
    out[tid + 256] = d1 * inv * g[tid + 256] + b[tid + 256];
}

} // namespace

extern "C" void kernel_launch(void* const* d_in, const int* in_sizes, int n_in,
                              void* d_out, int out_size, void* d_ws, size_t ws_size,
                              hipStream_t stream)
{
    const float* x      = (const float*)d_in[0];
    const float* fc1_w  = (const float*)d_in[1];
    const float* fc1_b  = (const float*)d_in[2];
    const float* cls    = (const float*)d_in[3];
    const float* l1_g   = (const float*)d_in[4];
    const float* l1_bb  = (const float*)d_in[5];
    const float* l1_qkv = (const float*)d_in[6];
    const float* l1_ow  = (const float*)d_in[7];
    const float* l1_ob  = (const float*)d_in[8];
    const float* l1_rw  = (const float*)d_in[9];
    const float* l2_g   = (const float*)d_in[10];
    const float* l2_bb  = (const float*)d_in[11];
    const float* l2_qkv = (const float*)d_in[12];
    const float* l2_ow  = (const float*)d_in[13];
    const float* l2_ob  = (const float*)d_in[14];
    const float* l2_rw  = (const float*)d_in[15];
    const float* p7w    = (const float*)d_in[16];
    const float* p7b    = (const float*)d_in[17];
    const float* p5w    = (const float*)d_in[18];
    const float* p5b    = (const float*)d_in[19];
    const float* p3w    = (const float*)d_in[20];
    const float* p3b    = (const float*)d_in[21];
    const float* ng     = (const float*)d_in[22];
    const float* nb     = (const float*)d_in[23];
    float* out = (float*)d_out;

    char* ws = (char*)d_ws;
    size_t off = 0;
    auto alloc = [&](size_t bytes) {
        char* p = ws + off;
        off += (bytes + 255) & ~(size_t)255;
        return (void*)p;
    };
    float* bufA = (float*)alloc((size_t)NP * HD * 4);
    float* bufB = (float*)alloc((size_t)NP * HD * 4);
    float* qh   = (float*)alloc((size_t)NH * NP * DH * 4);
    float* kh   = (float*)alloc((size_t)NH * NP * DH * 4);
    float* vh   = (float*)alloc((size_t)NH * NP * DH * 4);
    float* aout = (float*)alloc((size_t)NP * 64 * 4);
    float* ql   = (float*)alloc((size_t)NH * NL * DH * 4);
    float* klm  = (float*)alloc((size_t)NH * NL * DH * 4);
    float* wbuf = (float*)alloc((size_t)NH * NL * DH * 4);
    float* zwb  = (float*)alloc((size_t)NH * NL * DH * 4);
    float* a2   = (float*)alloc((size_t)NH * NL * NL * 4);
    float* zb0  = (float*)alloc((size_t)NH * NL * NL * 4);
    float* zb1  = (float*)alloc((size_t)NH * NL * NL * 4);
    float* azb  = (float*)alloc((size_t)NH * NL * NL * 4);
    float* tb   = (float*)alloc((size_t)NH * NL * NL * 4);
    float* ub   = (float*)alloc((size_t)NH * NL * NL * 4);
    unsigned* barbuf = (unsigned*)alloc(2048 * 4);
    float* plan  = (float*)alloc((size_t)CCH * NPIX * 4);
    float* plan2 = (float*)alloc((size_t)CCH * NPIX * 4);
    float* wcomb = (float*)alloc((size_t)HD * 49 * 4);
    float* bsum  = (float*)alloc((size_t)HD * 4);
    short* wt1   = (short*)alloc((size_t)HD * ID * 2);     // fc1_w^T bf16 [512][1024]
    short* wtq   = (short*)alloc((size_t)192 * HD * 2);    // qkv_w^T bf16 [192][512]
    short* xb    = (short*)alloc((size_t)NPIX * ID * 2);   // X bf16 [19600][1024]
    short* xpB   = (short*)alloc((size_t)NP * HD * 2);     // ln'ed tokens bf16
    (void)ws_size; (void)in_sizes; (void)n_in; (void)out_size;

    // fc1: cast X + weight, MFMA GEMM + gelu
    castX<<<(NPIX * ID / 8) / 256, 256, 0, stream>>>(x, xb);
    castT<<<dim3(HD / 32, ID / 32), 256, 0, stream>>>(fc1_w, wt1, ID, HD);
    gemm_fc1<<<dim3(154, 8), 256, 0, stream>>>(xb, wt1, fc1_b, bufA);
    cls_init<<<2, 256, 0, stream>>>(cls, bufA);

    auto attention = [&](float* hbuf, const float* lg, const float* lb,
                         const float* qkvw, const float* ow, const float* ob,
                         const float* rw) {
        ln_pad<<<NP, 256, 0, stream>>>(hbuf, lg, lb, xpB);
        castT<<<dim3(192 / 32, HD / 32), 256, 0, stream>>>(qkvw, wtq, HD, 192);
        gemm_qkv<<<dim3(NP / 64, 3), 256, 0, stream>>>(xpB, wtq, qh, kh, vh);
        landmarks<<<128, 256, 0, stream>>>(qh, kh, ql, klm);
        attn2_softmax<<<dim3(NL, NH), 256, 0, stream>>>(ql, klm, a2);
        pinv_init<<<8, 256, 0, stream>>>(barbuf);
        pinv_all<<<256, 256, 0, stream>>>(a2, zb0, zb1, azb, tb, ub, barbuf);
        attn3v<<<dim3(NL / 4, NH), 256, 0, stream>>>(kh, vh, ql, wbuf);
        zw_mul<<<64, 256, 0, stream>>>(zb0, wbuf, zwb);
        attn1_conv<<<dim3(77, NH), 256, 0, stream>>>(qh, vh, klm, zwb, rw, aout);
        outproj<<<(NT + 15) / 16, 512, 0, stream>>>(aout, ow, ob, hbuf);
    };

    attention(bufA, l1_g, l1_bb, l1_qkv, l1_ow, l1_ob, l1_rw);

    ppeg_wprep<<<(HD * 49 + HD + 255) / 256, 256, 0, stream>>>(p7w, p7b, p5w, p5b, p3w, p3b,
                                                               wcomb, bsum);
    copy512<<<1, 512, 0, stream>>>(bufA, bufB);
    constexpr int PTILES = (NPIX + 31) / 32;
    for (int ch0 = 0; ch0 < HD; ch0 += CCH) {
        ppeg_t1<<<dim3(PTILES, CCH / 32), 256, 0, stream>>>(bufA, plan, ch0);
        ppeg_conv<<<dim3(CCH, 4), 256, 0, stream>>>(plan, wcomb, plan2, ch0);
        ppeg_t2<<<dim3(PTILES, CCH / 32), 256, 0, stream>>>(plan2, bsum, bufB, ch0);
    }

    attention(bufB, l2_g, l2_bb, l2_qkv, l2_ow, l2_ob, l2_rw);
    final_ln<<<1, 256, 0, stream>>>(bufB, ng, nb, out);
}

// Round 7
// 1482.426 us; speedup vs baseline: 2.7789x; 2.7789x over previous
//
#include <hip/hip_runtime.h>

namespace {

constexpr int NP   = 19712;   // padded tokens (Nystrom)
constexpr int NT   = 19601;   // tokens incl cls
constexpr int NPIX = 19600;   // feature tokens (140x140)
constexpr int HD   = 512;     // hidden dim
constexpr int ID   = 1024;    // input dim
constexpr int NH   = 8;       // heads
constexpr int DH   = 8;       // dim per head
constexpr int NL   = 256;     // landmarks
constexpr int PADR = 111;     // left zero-pad rows
constexpr int SIDE = 140;
constexpr int CCH  = 128;     // ppeg channel chunk
constexpr int PW   = 148;     // padded image row stride (floats)

typedef __attribute__((ext_vector_type(8))) short bf16x8;
typedef __attribute__((ext_vector_type(4))) float f32x4;

#define F4MAD(a, s, v) { (a).x += (s)*(v).x; (a).y += (s)*(v).y; (a).z += (s)*(v).z; (a).w += (s)*(v).w; }
#define F4SCALE(a, s)  { (a).x *= (s); (a).y *= (s); (a).z *= (s); (a).w *= (s); }

__device__ inline short f2bf(float f) {
    union { float f; unsigned u; } v; v.f = f;
    unsigned r = v.u + 0x7fffu + ((v.u >> 16) & 1u);
    return (short)(r >> 16);
}

// ------------------------------------------------------------------
// cast X fp32 -> bf16 elementwise (same [m][k] layout)
// ------------------------------------------------------------------
__global__ void castX(const float* __restrict__ src, short* __restrict__ dst)
{
    size_t c = (size_t)blockIdx.x * 256 + threadIdx.x;   // chunk of 8
    const float4 x0 = *(const float4*)&src[c * 8];
    const float4 x1 = *(const float4*)&src[c * 8 + 4];
    bf16x8 p;
    p[0] = f2bf(x0.x); p[1] = f2bf(x0.y); p[2] = f2bf(x0.z); p[3] = f2bf(x0.w);
    p[4] = f2bf(x1.x); p[5] = f2bf(x1.y); p[6] = f2bf(x1.z); p[7] = f2bf(x1.w);
    *(bf16x8*)&dst[c * 8] = p;
}

// ------------------------------------------------------------------
// cast+transpose: dst[c][r] = bf16(src[r][c]); grid (C/32, R/32)
// ------------------------------------------------------------------
__global__ void castT(const float* __restrict__ src, short* __restrict__ dst, int R, int C)
{
    __shared__ float t[32][33];
    const int tx = threadIdx.x & 31, ty = threadIdx.x >> 5;
    const int c0 = blockIdx.x * 32, r0 = blockIdx.y * 32;
    #pragma unroll
    for (int j = 0; j < 4; ++j)
        t[ty + 8 * j][tx] = src[(size_t)(r0 + ty + 8 * j) * C + c0 + tx];
    __syncthreads();
    #pragma unroll
    for (int j = 0; j < 4; ++j)
        dst[(size_t)(c0 + ty + 8 * j) * R + r0 + tx] = f2bf(t[tx][ty + 8 * j]);
}

// ------------------------------------------------------------------
// fc1 MFMA: out[1+m][n] = gelu(Xb[m] @ W[:,n] + b[n]); M=19600 K=1024 N=512
// Xb bf16 [m][k], Wt bf16 [n][k]. 128x64 tile, 4 waves 2x2 (64x32 each).
// ------------------------------------------------------------------
__global__ __launch_bounds__(256) void gemm_fc1(const short* __restrict__ Xb,
                                                const short* __restrict__ Wt,
                                                const float* __restrict__ bias,
                                                float* __restrict__ out)
{
    __shared__ __align__(16) short As[128 * 40];
    __shared__ __align__(16) short Bs[64 * 40];
    const int tid  = threadIdx.x;
    const int row0 = blockIdx.x * 128;
    const int col0 = blockIdx.y * 64;
    const int wave = tid >> 6, lane = tid & 63;
    const int quad = lane >> 4, l16 = lane & 15;
    const int m_off = (wave >> 1) * 64, n_off = (wave & 1) * 32;
    f32x4 acc[4][2] = {};
    for (int k0 = 0; k0 < ID; k0 += 32) {
        #pragma unroll
        for (int seg = 0; seg < 2; ++seg) {
            int lin = tid + 256 * seg;
            int row = lin >> 2, kc = (lin & 3) * 8;
            int gr = row0 + row;
            bf16x8 pa = {};
            if (gr < NPIX) pa = *(const bf16x8*)&Xb[(size_t)gr * ID + k0 + kc];
            *(bf16x8*)&As[row * 40 + kc] = pa;
        }
        {
            int nrow = tid >> 2, kc = (tid & 3) * 8;
            *(bf16x8*)&Bs[nrow * 40 + kc] =
                *(const bf16x8*)&Wt[(size_t)(col0 + nrow) * ID + k0 + kc];
        }
        __syncthreads();
        bf16x8 af[4], bf[2];
        #pragma unroll
        for (int i = 0; i < 4; ++i)
            af[i] = *(const bf16x8*)&As[(m_off + i * 16 + l16) * 40 + quad * 8];
        #pragma unroll
        for (int i = 0; i < 2; ++i)
            bf[i] = *(const bf16x8*)&Bs[(n_off + i * 16 + l16) * 40 + quad * 8];
        #pragma unroll
        for (int mi = 0; mi < 4; ++mi)
            #pragma unroll
            for (int ni = 0; ni < 2; ++ni)
                acc[mi][ni] = __builtin_amdgcn_mfma_f32_16x16x32_bf16(af[mi], bf[ni], acc[mi][ni], 0, 0, 0);
        __syncthreads();
    }
    #pragma unroll
    for (int mi = 0; mi < 4; ++mi) {
        #pragma unroll
        for (int r = 0; r < 4; ++r) {
            int gr = row0 + m_off + mi * 16 + quad * 4 + r;
            if (gr >= NPIX) continue;
            #pragma unroll
            for (int ni = 0; ni < 2; ++ni) {
                int gc = col0 + n_off + ni * 16 + l16;
                float v = acc[mi][ni][r] + bias[gc];
                v = 0.5f * v * (1.f + erff(v * 0.70710678118654752f));
                out[(size_t)(gr + 1) * HD + gc] = v;
            }
        }
    }
}

// ------------------------------------------------------------------
// qkv MFMA: xpB(19712x512 bf16) @ Wt(192x512 bf16) -> qh/kh/vh fp32
// 64x64 tile, 4 waves 2x2 (32x32 each). grid (308, 3)
// ------------------------------------------------------------------
__global__ __launch_bounds__(256) void gemm_qkv(const short* __restrict__ xpB,
                                                const short* __restrict__ Wt,
                                                float* __restrict__ qh,
                                                float* __restrict__ kh,
                                                float* __restrict__ vh)
{
    __shared__ __align__(16) short As[64 * 40];
    __shared__ __align__(16) short Bs[64 * 40];
    const int tid  = threadIdx.x;
    const int row0 = blockIdx.x * 64;
    const int col0 = blockIdx.y * 64;
    const int wave = tid >> 6, lane = tid & 63;
    const int quad = lane >> 4, l16 = lane & 15;
    const int m_off = (wave >> 1) * 32, n_off = (wave & 1) * 32;
    f32x4 acc[2][2] = {};
    for (int k0 = 0; k0 < HD; k0 += 32) {
        {
            int row = tid >> 2, kc = (tid & 3) * 8;
            *(bf16x8*)&As[row * 40 + kc] =
                *(const bf16x8*)&xpB[(size_t)(row0 + row) * HD + k0 + kc];
            *(bf16x8*)&Bs[row * 40 + kc] =
                *(const bf16x8*)&Wt[(size_t)(col0 + row) * HD + k0 + kc];
        }
        __syncthreads();
        bf16x8 af[2], bf[2];
        #pragma unroll
        for (int i = 0; i < 2; ++i) {
            af[i] = *(const bf16x8*)&As[(m_off + i * 16 + l16) * 40 + quad * 8];
            bf[i] = *(const bf16x8*)&Bs[(n_off + i * 16 + l16) * 40 + quad * 8];
        }
        #pragma unroll
        for (int mi = 0; mi < 2; ++mi)
            #pragma unroll
            for (int ni = 0; ni < 2; ++ni)
                acc[mi][ni] = __builtin_amdgcn_mfma_f32_16x16x32_bf16(af[mi], bf[ni], acc[mi][ni], 0, 0, 0);
        __syncthreads();
    }
    const int which = blockIdx.y;
    float* dst = (which == 0) ? qh : (which == 1) ? kh : vh;
    const float scale = (which == 0) ? 0.35355339059327373f : 1.f;
    #pragma unroll
    for (int mi = 0; mi < 2; ++mi) {
        #pragma unroll
        for (int r = 0; r < 4; ++r) {
            int gr = row0 + m_off + mi * 16 + quad * 4 + r;
            #pragma unroll
            for (int ni = 0; ni < 2; ++ni) {
                int n = n_off + ni * 16 + l16;     // 0..63 local
                int hh = n >> 3, d = n & 7;
                dst[((size_t)hh * NP + gr) * DH + d] = acc[mi][ni][r] * scale;
            }
        }
    }
}

__global__ void cls_init(const float* __restrict__ cls, float* __restrict__ h)
{
    int t = blockIdx.x * 256 + threadIdx.x;
    if (t < HD) h[t] = cls[t];
}

__global__ void copy512(const float* __restrict__ src, float* __restrict__ dst)
{
    dst[threadIdx.x] = src[threadIdx.x];
}

// ------------------------------------------------------------------
// layernorm rows of h into xp (bf16), first 111 rows zero
// ------------------------------------------------------------------
__global__ void ln_pad(const float* __restrict__ h, const float* __restrict__ g,
                       const float* __restrict__ b, short* __restrict__ xp)
{
    const int row = blockIdx.x;
    const int tid = threadIdx.x;
    short* dst = xp + (size_t)row * HD;
    if (row < PADR) { dst[tid] = 0; dst[tid + 256] = 0; return; }
    const float* src = h + (size_t)(row - PADR) * HD;
    float v0 = src[tid], v1 = src[tid + 256];
    __shared__ float red[256];
    red[tid] = v0 + v1;
    __syncthreads();
    for (int off = 128; off > 0; off >>= 1) {
        if (tid < off) red[tid] += red[tid + off];
        __syncthreads();
    }
    float mu = red[0] * (1.f / HD);
    __syncthreads();
    float d0 = v0 - mu, d1 = v1 - mu;
    red[tid] = d0 * d0 + d1 * d1;
    __syncthreads();
    for (int off = 128; off > 0; off >>= 1) {
        if (tid < off) red[tid] += red[tid + off];
        __syncthreads();
    }
    float inv = rsqrtf(red[0] * (1.f / HD) + 1e-5f);
    dst[tid]       = f2bf(d0 * inv * g[tid] + b[tid]);
    dst[tid + 256] = f2bf(d1 * inv * g[tid + 256] + b[tid + 256]);
}

// ------------------------------------------------------------------
// landmark means
// ------------------------------------------------------------------
__global__ void landmarks(const float* __restrict__ qh, const float* __restrict__ kh,
                          float* __restrict__ ql, float* __restrict__ kl)
{
    int idx = blockIdx.x * 256 + threadIdx.x;
    int sel = idx >> 14;
    int rem = idx & 16383;
    int h = rem >> 11;
    int i = (rem >> 3) & 255;
    int d = rem & 7;
    const float* src = sel ? kh : qh;
    size_t base = ((size_t)h * NP + (size_t)i * 77) * DH + d;
    float s = 0.f;
    for (int j = 0; j < 77; ++j) s += src[base + (size_t)j * DH];
    (sel ? kl : ql)[((size_t)h * NL + i) * DH + d] = s * (1.f / 77.f);
}

// ------------------------------------------------------------------
// attn2 = softmax(q_l @ k_l^T)
// ------------------------------------------------------------------
__global__ void attn2_softmax(const float* __restrict__ ql, const float* __restrict__ kl,
                              float* __restrict__ a)
{
    const int i = blockIdx.x, h = blockIdx.y, j = threadIdx.x;
    __shared__ float sq[8];
    __shared__ float red[256];
    if (j < 8) sq[j] = ql[((size_t)h * NL + i) * DH + j];
    __syncthreads();
    const float* kr = kl + ((size_t)h * NL + j) * DH;
    float s = 0.f;
    #pragma unroll
    for (int d = 0; d < 8; ++d) s += sq[d] * kr[d];
    red[j] = s;
    __syncthreads();
    for (int off = 128; off > 0; off >>= 1) {
        if (j < off) red[j] = fmaxf(red[j], red[j + off]);
        __syncthreads();
    }
    float mx = red[0];
    __syncthreads();
    float e = __expf(s - mx);
    red[j] = e;
    __syncthreads();
    for (int off = 128; off > 0; off >>= 1) {
        if (j < off) red[j] += red[j + off];
        __syncthreads();
    }
    a[((size_t)h * NL + i) * NL + j] = e / red[0];
}

// ------------------------------------------------------------------
// pinv init: rowsum/colsum maxima
// ------------------------------------------------------------------
__global__ void pinv_norms(const float* __restrict__ a, float* __restrict__ part)
{
    const int h = blockIdx.x & 7;
    const int mode = blockIdx.x >> 3;
    const int tid = threadIdx.x;
    const float* ah = a + (size_t)h * NL * NL;
    float s = 0.f;
    if (mode == 0) { for (int j = 0; j < NL; ++j) s += fabsf(ah[tid * NL + j]); }
    else           { for (int i = 0; i < NL; ++i) s += fabsf(ah[i * NL + tid]); }
    __shared__ float red[256];
    red[tid] = s;
    __syncthreads();
    for (int off = 128; off > 0; off >>= 1) {
        if (tid < off) red[tid] = fmaxf(red[tid], red[tid + off]);
        __syncthreads();
    }
    if (tid == 0) part[mode * 8 + h] = red[0];
}

__global__ void z0_init(const float* __restrict__ a, const float* __restrict__ part,
                        float* __restrict__ z)
{
    float s1 = part[0], s2 = part[8];
    #pragma unroll
    for (int h = 1; h < 8; ++h) { s1 = fmaxf(s1, part[h]); s2 = fmaxf(s2, part[8 + h]); }
    float inv = 1.f / (s1 * s2);
    int idx = blockIdx.x * 256 + threadIdx.x;
    int h = idx >> 16;
    int rem = idx & 65535;
    int i = rem >> 8, j = rem & 255;
    z[idx] = a[((size_t)h * NL + j) * NL + i] * inv;
}

// ------------------------------------------------------------------
// batched 256x256x256: D = alpha*(A@B) + beta*A   grid (8,4,8) 32x64 tiles
// ------------------------------------------------------------------
__global__ void mm256(const float* __restrict__ A, const float* __restrict__ B,
                      float* __restrict__ D, float alpha, float beta)
{
    const int h = blockIdx.z;
    const float* Ah = A + (size_t)h * NL * NL;
    const float* Bh = B + (size_t)h * NL * NL;
    float* Dh = D + (size_t)h * NL * NL;
    __shared__ __align__(16) float As[16][36];
    __shared__ __align__(16) float Bs[16][68];
    const int tid = threadIdx.x;
    const int tx = tid & 15, ty = tid >> 4;
    const int row0 = blockIdx.x * 32;
    const int col0 = blockIdx.y * 64;
    float acc[2][4] = {};
    const int ar = tid >> 3;
    const int ak = (tid & 7) * 2;
    const int bk = tid >> 4;
    const int bj = (tid & 15) * 4;
    for (int k0 = 0; k0 < NL; k0 += 16) {
        float2 av = *(const float2*)&Ah[(size_t)(row0 + ar) * NL + k0 + ak];
        As[ak][ar] = av.x; As[ak + 1][ar] = av.y;
        *(float4*)&Bs[bk][bj] = *(const float4*)&Bh[(size_t)(k0 + bk) * NL + col0 + bj];
        __syncthreads();
        #pragma unroll
        for (int k = 0; k < 16; ++k) {
            float2 a = *(const float2*)&As[k][ty * 2];
            float4 b = *(const float4*)&Bs[k][tx * 4];
            acc[0][0] += a.x * b.x; acc[0][1] += a.x * b.y; acc[0][2] += a.x * b.z; acc[0][3] += a.x * b.w;
            acc[1][0] += a.y * b.x; acc[1][1] += a.y * b.y; acc[1][2] += a.y * b.z; acc[1][3] += a.y * b.w;
        }
        __syncthreads();
    }
    #pragma unroll
    for (int r = 0; r < 2; ++r) {
        int gr = row0 + ty * 2 + r;
        #pragma unroll
        for (int c = 0; c < 4; ++c) {
            int gc = col0 + tx * 4 + c;
            Dh[(size_t)gr * NL + gc] = alpha * acc[r][c] + beta * Ah[(size_t)gr * NL + gc];
        }
    }
}

// ------------------------------------------------------------------
// attn3 @ v: 4 landmarks/block, branchless online softmax, shfl merge
// ------------------------------------------------------------------
__global__ void attn3v(const float* __restrict__ kh, const float* __restrict__ vh,
                       const float* __restrict__ ql, float* __restrict__ wbuf)
{
    const int i0 = blockIdx.x * 4, h = blockIdx.y, tid = threadIdx.x;
    __shared__ float sq[4][8];
    __shared__ float wred[4][4][10];
    if (tid < 32) sq[tid >> 3][tid & 7] = ql[((size_t)h * NL + i0 + (tid >> 3)) * DH + (tid & 7)];
    __syncthreads();
    float q[4][8];
    #pragma unroll
    for (int li = 0; li < 4; ++li)
        #pragma unroll
        for (int d = 0; d < 8; ++d) q[li][d] = sq[li][d];
    const float* kb = kh + (size_t)h * NP * DH;
    const float* vb = vh + (size_t)h * NP * DH;
    float m[4] = {-1e30f, -1e30f, -1e30f, -1e30f};
    float den[4] = {};
    float acc[4][8] = {};
    for (int t = tid; t < NP; t += 256) {
        const float4 k0 = *(const float4*)&kb[(size_t)t * 8];
        const float4 k1 = *(const float4*)&kb[(size_t)t * 8 + 4];
        const float4 v0 = *(const float4*)&vb[(size_t)t * 8];
        const float4 v1 = *(const float4*)&vb[(size_t)t * 8 + 4];
        float vv[8] = {v0.x, v0.y, v0.z, v0.w, v1.x, v1.y, v1.z, v1.w};
        float kk[8] = {k0.x, k0.y, k0.z, k0.w, k1.x, k1.y, k1.z, k1.w};
        #pragma unroll
        for (int li = 0; li < 4; ++li) {
            float s = 0.f;
            #pragma unroll
            for (int d = 0; d < 8; ++d) s += q[li][d] * kk[d];
            float nm = fmaxf(m[li], s);
            float sc = __expf(m[li] - nm);
            float e  = __expf(s - nm);
            m[li] = nm;
            den[li] = den[li] * sc + e;
            #pragma unroll
            for (int d = 0; d < 8; ++d) acc[li][d] = acc[li][d] * sc + e * vv[d];
        }
    }
    #pragma unroll
    for (int off = 1; off < 64; off <<= 1) {
        #pragma unroll
        for (int li = 0; li < 4; ++li) {
            float mo = __shfl_xor(m[li], off);
            float dn = __shfl_xor(den[li], off);
            float ao[8];
            #pragma unroll
            for (int d = 0; d < 8; ++d) ao[d] = __shfl_xor(acc[li][d], off);
            float nm = fmaxf(m[li], mo);
            float s1 = __expf(m[li] - nm), s2 = __expf(mo - nm);
            den[li] = den[li] * s1 + dn * s2;
            #pragma unroll
            for (int d = 0; d < 8; ++d) acc[li][d] = acc[li][d] * s1 + ao[d] * s2;
            m[li] = nm;
        }
    }
    const int wave = tid >> 6, lane = tid & 63;
    if (lane == 0) {
        #pragma unroll
        for (int li = 0; li < 4; ++li) {
            wred[wave][li][0] = m[li];
            wred[wave][li][1] = den[li];
            #pragma unroll
            for (int d = 0; d < 8; ++d) wred[wave][li][2 + d] = acc[li][d];
        }
    }
    __syncthreads();
    if (tid < 4) {
        const int li = tid;
        float M = wred[0][li][0], D_ = wred[0][li][1];
        float A[8];
        #pragma unroll
        for (int d = 0; d < 8; ++d) A[d] = wred[0][li][2 + d];
        #pragma unroll
        for (int w = 1; w < 4; ++w) {
            float mo = wred[w][li][0], dn = wred[w][li][1];
            float nm = fmaxf(M, mo);
            float s1 = __expf(M - nm), s2 = __expf(mo - nm);
            D_ = D_ * s1 + dn * s2;
            #pragma unroll
            for (int d = 0; d < 8; ++d) A[d] = A[d] * s1 + wred[w][li][2 + d] * s2;
            M = nm;
        }
        #pragma unroll
        for (int d = 0; d < 8; ++d)
            wbuf[((size_t)h * NL + i0 + li) * DH + d] = A[d] / D_;
    }
}

// ------------------------------------------------------------------
// zw[h][i][d] = sum_j z[h][i][j] * w[h][j][d]
// ------------------------------------------------------------------
__global__ void zw_mul(const float* __restrict__ z, const float* __restrict__ w,
                       float* __restrict__ zw)
{
    int idx = blockIdx.x * 256 + threadIdx.x;
    int h = idx >> 11;
    int rem = idx & 2047;
    int i = rem >> 3, d = rem & 7;
    const float* zr = z + ((size_t)h * NL + i) * NL;
    const float* wb = w + (size_t)h * NL * DH + d;
    float s = 0.f;
    for (int j = 0; j < NL; ++j) s += zr[j] * wb[(size_t)j * DH];
    zw[idx] = s;
}

// ------------------------------------------------------------------
// attn1 fused + dwconv33(v), branchless online softmax
// ------------------------------------------------------------------
__global__ void attn1_conv(const float* __restrict__ qh, const float* __restrict__ vh,
                           const float* __restrict__ klg, const float* __restrict__ zwg,
                           const float* __restrict__ rw, float* __restrict__ aout)
{
    const int h = blockIdx.y;
    __shared__ __align__(16) float kl[NL * DH];
    __shared__ __align__(16) float zw[NL * DH];
    const int tid = threadIdx.x;
    for (int q = tid; q < NL * DH; q += 256) {
        kl[q] = klg[(size_t)h * NL * DH + q];
        zw[q] = zwg[(size_t)h * NL * DH + q];
    }
    __syncthreads();
    const int r = blockIdx.x * 256 + tid;
    if (r >= NT) return;
    const int t = r + PADR;
    const float* qp = qh + ((size_t)h * NP + t) * DH;
    float4 q0 = *(const float4*)qp;
    float4 q1 = *(const float4*)(qp + 4);
    float m = -1e30f, den = 0.f;
    float4 acc0 = make_float4(0.f, 0.f, 0.f, 0.f);
    float4 acc1 = make_float4(0.f, 0.f, 0.f, 0.f);
    for (int i = 0; i < NL; ++i) {
        float4 k0 = *(const float4*)&kl[i * 8];
        float4 k1 = *(const float4*)&kl[i * 8 + 4];
        float s = q0.x * k0.x + q0.y * k0.y + q0.z * k0.z + q0.w * k0.w
                + q1.x * k1.x + q1.y * k1.y + q1.z * k1.z + q1.w * k1.w;
        float nm = fmaxf(m, s);
        float sc = __expf(m - nm);
        float e  = __expf(s - nm);
        m = nm;
        den = den * sc + e;
        float4 z0 = *(const float4*)&zw[i * 8];
        float4 z1 = *(const float4*)&zw[i * 8 + 4];
        acc0.x = acc0.x * sc + e * z0.x; acc0.y = acc0.y * sc + e * z0.y;
        acc0.z = acc0.z * sc + e * z0.z; acc0.w = acc0.w * sc + e * z0.w;
        acc1.x = acc1.x * sc + e * z1.x; acc1.y = acc1.y * sc + e * z1.y;
        acc1.z = acc1.z * sc + e * z1.z; acc1.w = acc1.w * sc + e * z1.w;
    }
    float inv = 1.f / den;
    F4SCALE(acc0, inv); F4SCALE(acc1, inv);
    const float* vb = vh + (size_t)h * NP * DH;
    #pragma unroll
    for (int j = 0; j < 33; ++j) {
        int tp = t - 16 + j;
        if (tp >= NP) continue;
        float wv = rw[h * 33 + j];
        float4 v0 = *(const float4*)&vb[(size_t)tp * 8];
        float4 v1 = *(const float4*)&vb[(size_t)tp * 8 + 4];
        F4MAD(acc0, wv, v0); F4MAD(acc1, wv, v1);
    }
    float* op = aout + (size_t)r * 64 + h * 8;
    *(float4*)op = acc0;
    *(float4*)(op + 4) = acc1;
}

// ------------------------------------------------------------------
// out-proj + residual: 16 rows/block
// ------------------------------------------------------------------
__global__ void outproj(const float* __restrict__ aout, const float* __restrict__ W,
                        const float* __restrict__ bias, float* __restrict__ h)
{
    const int r0 = blockIdx.x * 16;
    const int tid = threadIdx.x;   // 512
    __shared__ float ao[16][64];
    #pragma unroll
    for (int s = 0; s < 2; ++s) {
        int idx = tid + s * 512;
        int rr = idx >> 6, kk = idx & 63;
        int gr = r0 + rr;
        ao[rr][kk] = (gr < NT) ? aout[(size_t)gr * 64 + kk] : 0.f;
    }
    __syncthreads();
    float acc[16] = {};
    for (int k = 0; k < 64; ++k) {
        float wv = W[(size_t)k * HD + tid];
        #pragma unroll
        for (int r = 0; r < 16; ++r) acc[r] += ao[r][k] * wv;
    }
    float bv = bias[tid];
    #pragma unroll
    for (int r = 0; r < 16; ++r) {
        int gr = r0 + r;
        if (gr < NT) h[(size_t)gr * HD + tid] += acc[r] + bv;
    }
}

// ------------------------------------------------------------------
// PPEG
// ------------------------------------------------------------------
__global__ void ppeg_wprep(const float* __restrict__ w7, const float* __restrict__ b7,
                           const float* __restrict__ w5, const float* __restrict__ b5,
                           const float* __restrict__ w3, const float* __restrict__ b3,
                           float* __restrict__ wc, float* __restrict__ bsum)
{
    int idx = blockIdx.x * 256 + threadIdx.x;
    if (idx < HD * 49) {
        int c = idx / 49, t = idx - c * 49;
        int dy = t / 7 - 3, dx = t % 7 - 3;
        float v = w7[idx];
        if (dy >= -2 && dy <= 2 && dx >= -2 && dx <= 2) v += w5[c * 25 + (dy + 2) * 5 + (dx + 2)];
        if (dy >= -1 && dy <= 1 && dx >= -1 && dx <= 1) v += w3[c * 9 + (dy + 1) * 3 + (dx + 1)];
        if (t == 24) v += 1.f;
        wc[idx] = v;
    } else if (idx < HD * 49 + HD) {
        int c = idx - HD * 49;
        bsum[c] = b7[c] + b5[c] + b3[c];
    }
}

__global__ void ppeg_t1(const float* __restrict__ hin, float* __restrict__ plan, int ch0)
{
    __shared__ float tile[32][33];
    const int tx = threadIdx.x & 31, ty = threadIdx.x >> 5;
    const int p0 = blockIdx.x * 32;
    const int c0 = ch0 + blockIdx.y * 32;
    #pragma unroll
    for (int j = 0; j < 4; ++j) {
        int p = p0 + ty + j * 8;
        tile[ty + j * 8][tx] = (p < NPIX) ? hin[(size_t)(1 + p) * HD + c0 + tx] : 0.f;
    }
    __syncthreads();
    #pragma unroll
    for (int j = 0; j < 4; ++j) {
        int p = p0 + tx;
        int cc = ty + j * 8;
        if (p < NPIX) plan[(size_t)(blockIdx.y * 32 + cc) * NPIX + p] = tile[tx][cc];
    }
}

__global__ __launch_bounds__(256) void ppeg_conv(const float* __restrict__ plan,
                                                 const float* __restrict__ wc,
                                                 float* __restrict__ plan2, int ch0)
{
    __shared__ __align__(16) float img[41 * PW];
    const int tid = threadIdx.x;
    const int cl = blockIdx.x;
    const int yq = blockIdx.y;
    for (int i = tid; i < 41 * PW; i += 256) img[i] = 0.f;
    __syncthreads();
    const float* src = plan + (size_t)cl * NPIX;
    for (int i = tid; i < 41 * SIDE; i += 256) {
        int ly = i / SIDE, x = i - ly * SIDE;
        int y = yq * 35 - 3 + ly;
        if (y >= 0 && y < SIDE) img[ly * PW + x + 3] = src[y * SIDE + x];
    }
    const float* w = wc + (size_t)(ch0 + cl) * 49;
    float wr[49];
    #pragma unroll
    for (int t = 0; t < 49; ++t) wr[t] = w[t];
    __syncthreads();
    float* dst = plan2 + (size_t)cl * NPIX;
    for (int g = tid; g < 35 * 35; g += 256) {
        int yl = g / 35, x0 = (g - yl * 35) * 4;
        float acc0 = 0.f, acc1 = 0.f, acc2 = 0.f, acc3 = 0.f;
        #pragma unroll
        for (int a = 0; a < 7; ++a) {
            const float* row = &img[(yl + a) * PW + x0];
            float4 A = *(const float4*)(row);
            float4 B = *(const float4*)(row + 4);
            float4 C = *(const float4*)(row + 8);
            float e0 = A.x, e1 = A.y, e2 = A.z, e3 = A.w;
            float e4 = B.x, e5 = B.y, e6 = B.z, e7 = B.w;
            float e8 = C.x, e9 = C.y;
            const float w0 = wr[a*7+0], w1 = wr[a*7+1], w2 = wr[a*7+2], w3v = wr[a*7+3];
            const float w4 = wr[a*7+4], w5v = wr[a*7+5], w6 = wr[a*7+6];
            acc0 += w0*e0 + w1*e1 + w2*e2 + w3v*e3 + w4*e4 + w5v*e5 + w6*e6;
            acc1 += w0*e1 + w1*e2 + w2*e3 + w3v*e4 + w4*e5 + w5v*e6 + w6*e7;
            acc2 += w0*e2 + w1*e3 + w2*e4 + w3v*e5 + w4*e6 + w5v*e7 + w6*e8;
            acc3 += w0*e3 + w1*e4 + w2*e5 + w3v*e6 + w4*e7 + w5v*e8 + w6*e9;
        }
        *(float4*)&dst[(yq * 35 + yl) * SIDE + x0] = make_float4(acc0, acc1, acc2, acc3);
    }
}

__global__ void ppeg_t2(const float* __restrict__ plan2, const float* __restrict__ bsum,
                        float* __restrict__ hout, int ch0)
{
    __shared__ float tile[32][33];
    const int tx = threadIdx.x & 31, ty = threadIdx.x >> 5;
    const int p0 = blockIdx.x * 32;
    #pragma unroll
    for (int j = 0; j < 4; ++j) {
        int p = p0 + tx;
        int cc = ty + j * 8;
        tile[tx][cc] = (p < NPIX) ? plan2[(size_t)(blockIdx.y * 32 + cc) * NPIX + p] : 0.f;
    }
    __syncthreads();
    const int c0 = ch0 + blockIdx.y * 32;
    float bv = bsum[c0 + tx];
    #pragma unroll
    for (int j = 0; j < 4; ++j) {
        int p = p0 + ty + j * 8;
        if (p < NPIX) hout[(size_t)(1 + p) * HD + c0 + tx] = tile[ty + j * 8][tx] + bv;
    }
}

// ------------------------------------------------------------------
// final layernorm of row 0
// ------------------------------------------------------------------
__global__ void final_ln(const float* __restrict__ h, const float* __restrict__ g,
                         const float* __restrict__ b, float* __restrict__ out)
{
    const int tid = threadIdx.x;
    float v0 = h[tid], v1 = h[tid + 256];
    __shared__ float red[256];
    red[tid] = v0 + v1;
    __syncthreads();
    for (int off = 128; off > 0; off >>= 1) {
        if (tid < off) red[tid] += red[tid + off];
        __syncthreads();
    }
    float mu = red[0] * (1.f / HD);
    __syncthreads();
    float d0 = v0 - mu, d1 = v1 - mu;
    red[tid] = d0 * d0 + d1 * d1;
    __syncthreads();
    for (int off = 128; off > 0; off >>= 1) {
        if (tid < off) red[tid] += red[tid + off];
        __syncthreads();
    }
    float inv = rsqrtf(red[0] * (1.f / HD) + 1e-5f);
    out[tid]       = d0 * inv * g[tid] + b[tid];
    out[tid + 256] = d1 * inv * g[tid + 256] + b[tid + 256];
}

} // namespace

extern "C" void kernel_launch(void* const* d_in, const int* in_sizes, int n_in,
                              void* d_out, int out_size, void* d_ws, size_t ws_size,
                              hipStream_t stream)
{
    const float* x      = (const float*)d_in[0];
    const float* fc1_w  = (const float*)d_in[1];
    const float* fc1_b  = (const float*)d_in[2];
    const float* cls    = (const float*)d_in[3];
    const float* l1_g   = (const float*)d_in[4];
    const float* l1_bb  = (const float*)d_in[5];
    const float* l1_qkv = (const float*)d_in[6];
    const float* l1_ow  = (const float*)d_in[7];
    const float* l1_ob  = (const float*)d_in[8];
    const float* l1_rw  = (const float*)d_in[9];
    const float* l2_g   = (const float*)d_in[10];
    const float* l2_bb  = (const float*)d_in[11];
    const float* l2_qkv = (const float*)d_in[12];
    const float* l2_ow  = (const float*)d_in[13];
    const float* l2_ob  = (const float*)d_in[14];
    const float* l2_rw  = (const float*)d_in[15];
    const float* p7w    = (const float*)d_in[16];
    const float* p7b    = (const float*)d_in[17];
    const float* p5w    = (const float*)d_in[18];
    const float* p5b    = (const float*)d_in[19];
    const float* p3w    = (const float*)d_in[20];
    const float* p3b    = (const float*)d_in[21];
    const float* ng     = (const float*)d_in[22];
    const float* nb     = (const float*)d_in[23];
    float* out = (float*)d_out;

    char* ws = (char*)d_ws;
    size_t off = 0;
    auto alloc = [&](size_t bytes) {
        char* p = ws + off;
        off += (bytes + 255) & ~(size_t)255;
        return (void*)p;
    };
    float* bufA = (float*)alloc((size_t)NP * HD * 4);
    float* bufB = (float*)alloc((size_t)NP * HD * 4);
    float* qh   = (float*)alloc((size_t)NH * NP * DH * 4);
    float* kh   = (float*)alloc((size_t)NH * NP * DH * 4);
    float* vh   = (float*)alloc((size_t)NH * NP * DH * 4);
    float* aout = (float*)alloc((size_t)NP * 64 * 4);
    float* ql   = (float*)alloc((size_t)NH * NL * DH * 4);
    float* klm  = (float*)alloc((size_t)NH * NL * DH * 4);
    float* wbuf = (float*)alloc((size_t)NH * NL * DH * 4);
    float* zwb  = (float*)alloc((size_t)NH * NL * DH * 4);
    float* a2   = (float*)alloc((size_t)NH * NL * NL * 4);
    float* zb0  = (float*)alloc((size_t)NH * NL * NL * 4);
    float* zb1  = (float*)alloc((size_t)NH * NL * NL * 4);
    float* azb  = (float*)alloc((size_t)NH * NL * NL * 4);
    float* tb   = (float*)alloc((size_t)NH * NL * NL * 4);
    float* ub   = (float*)alloc((size_t)NH * NL * NL * 4);
    float* part = (float*)alloc(256);
    float* plan  = (float*)alloc((size_t)CCH * NPIX * 4);
    float* plan2 = (float*)alloc((size_t)CCH * NPIX * 4);
    float* wcomb = (float*)alloc((size_t)HD * 49 * 4);
    float* bsum  = (float*)alloc((size_t)HD * 4);
    short* wt1   = (short*)alloc((size_t)HD * ID * 2);     // fc1_w^T bf16 [512][1024]
    short* wtq   = (short*)alloc((size_t)192 * HD * 2);    // qkv_w^T bf16 [192][512]
    short* xb    = (short*)alloc((size_t)NPIX * ID * 2);   // X bf16 [19600][1024]
    short* xpB   = (short*)alloc((size_t)NP * HD * 2);     // ln'ed tokens bf16
    (void)ws_size; (void)in_sizes; (void)n_in; (void)out_size;

    // fc1: cast X + weight, MFMA GEMM + gelu
    castX<<<(NPIX * ID / 8) / 256, 256, 0, stream>>>(x, xb);
    castT<<<dim3(HD / 32, ID / 32), 256, 0, stream>>>(fc1_w, wt1, ID, HD);
    gemm_fc1<<<dim3(154, 8), 256, 0, stream>>>(xb, wt1, fc1_b, bufA);
    cls_init<<<2, 256, 0, stream>>>(cls, bufA);

    auto attention = [&](float* hbuf, const float* lg, const float* lb,
                         const float* qkvw, const float* ow, const float* ob,
                         const float* rw) {
        ln_pad<<<NP, 256, 0, stream>>>(hbuf, lg, lb, xpB);
        castT<<<dim3(192 / 32, HD / 32), 256, 0, stream>>>(qkvw, wtq, HD, 192);
        gemm_qkv<<<dim3(NP / 64, 3), 256, 0, stream>>>(xpB, wtq, qh, kh, vh);
        landmarks<<<128, 256, 0, stream>>>(qh, kh, ql, klm);
        attn2_softmax<<<dim3(NL, NH), 256, 0, stream>>>(ql, klm, a2);
        pinv_norms<<<16, 256, 0, stream>>>(a2, part);
        z0_init<<<2048, 256, 0, stream>>>(a2, part, zb0);
        float* zc = zb0;
        float* zn = zb1;
        for (int it = 0; it < 6; ++it) {
            mm256<<<dim3(8, 4, 8), 256, 0, stream>>>(a2, zc, azb, 1.f, 0.f);
            mm256<<<dim3(8, 4, 8), 256, 0, stream>>>(azb, azb, tb, -1.f, 7.f);
            mm256<<<dim3(8, 4, 8), 256, 0, stream>>>(azb, tb, ub, -1.f, 15.f);
            mm256<<<dim3(8, 4, 8), 256, 0, stream>>>(zc, ub, zn, -0.25f, 3.25f);
            float* tmp = zc; zc = zn; zn = tmp;
        }
        attn3v<<<dim3(NL / 4, NH), 256, 0, stream>>>(kh, vh, ql, wbuf);
        zw_mul<<<64, 256, 0, stream>>>(zc, wbuf, zwb);
        attn1_conv<<<dim3(77, NH), 256, 0, stream>>>(qh, vh, klm, zwb, rw, aout);
        outproj<<<(NT + 15) / 16, 512, 0, stream>>>(aout, ow, ob, hbuf);
    };

    attention(bufA, l1_g, l1_bb, l1_qkv, l1_ow, l1_ob, l1_rw);

    ppeg_wprep<<<(HD * 49 + HD + 255) / 256, 256, 0, stream>>>(p7w, p7b, p5w, p5b, p3w, p3b,
                                                               wcomb, bsum);
    copy512<<<1, 512, 0, stream>>>(bufA, bufB);
    constexpr int PTILES = (NPIX + 31) / 32;
    for (int ch0 = 0; ch0 < HD; ch0 += CCH) {
        ppeg_t1<<<dim3(PTILES, CCH / 32), 256, 0, stream>>>(bufA, plan, ch0);
        ppeg_conv<<<dim3(CCH, 4), 256, 0, stream>>>(plan, wcomb, plan2, ch0);
        ppeg_t2<<<dim3(PTILES, CCH / 32), 256, 0, stream>>>(plan2, bsum, bufB, ch0);
    }

    attention(bufB, l2_g, l2_bb, l2_qkv, l2_ow, l2_ob, l2_rw);
    final_ln<<<1, 256, 0, stream>>>(bufB, ng, nb, out);
}

// Round 8
// 1458.599 us; speedup vs baseline: 2.8243x; 1.0163x over previous
//
#include <hip/hip_runtime.h>

namespace {

constexpr int NP   = 19712;   // padded tokens (Nystrom)
constexpr int NT   = 19601;   // tokens incl cls
constexpr int NPIX = 19600;   // feature tokens (140x140)
constexpr int HD   = 512;     // hidden dim
constexpr int ID   = 1024;    // input dim
constexpr int NH   = 8;       // heads
constexpr int DH   = 8;       // dim per head
constexpr int NL   = 256;     // landmarks
constexpr int PADR = 111;     // left zero-pad rows
constexpr int SIDE = 140;
constexpr int CCH  = 128;     // ppeg channel chunk
constexpr int PW   = 148;     // padded image row stride (floats)
constexpr int CKT  = NP / 4;  // attn3v token chunk = 4928

typedef __attribute__((ext_vector_type(8))) short bf16x8;
typedef __attribute__((ext_vector_type(4))) float f32x4;

#define F4MAD(a, s, v) { (a).x += (s)*(v).x; (a).y += (s)*(v).y; (a).z += (s)*(v).z; (a).w += (s)*(v).w; }
#define F4SCALE(a, s)  { (a).x *= (s); (a).y *= (s); (a).z *= (s); (a).w *= (s); }

__device__ inline short f2bf(float f) {
    union { float f; unsigned u; } v; v.f = f;
    unsigned r = v.u + 0x7fffu + ((v.u >> 16) & 1u);
    return (short)(r >> 16);
}

// ------------------------------------------------------------------
// cast X fp32 -> bf16 elementwise
// ------------------------------------------------------------------
__global__ void castX(const float* __restrict__ src, short* __restrict__ dst)
{
    size_t c = (size_t)blockIdx.x * 256 + threadIdx.x;
    const float4 x0 = *(const float4*)&src[c * 8];
    const float4 x1 = *(const float4*)&src[c * 8 + 4];
    bf16x8 p;
    p[0] = f2bf(x0.x); p[1] = f2bf(x0.y); p[2] = f2bf(x0.z); p[3] = f2bf(x0.w);
    p[4] = f2bf(x1.x); p[5] = f2bf(x1.y); p[6] = f2bf(x1.z); p[7] = f2bf(x1.w);
    *(bf16x8*)&dst[c * 8] = p;
}

// ------------------------------------------------------------------
// cast+transpose: dst[c][r] = bf16(src[r][c]); grid (C/32, R/32)
// ------------------------------------------------------------------
__global__ void castT(const float* __restrict__ src, short* __restrict__ dst, int R, int C)
{
    __shared__ float t[32][33];
    const int tx = threadIdx.x & 31, ty = threadIdx.x >> 5;
    const int c0 = blockIdx.x * 32, r0 = blockIdx.y * 32;
    #pragma unroll
    for (int j = 0; j < 4; ++j)
        t[ty + 8 * j][tx] = src[(size_t)(r0 + ty + 8 * j) * C + c0 + tx];
    __syncthreads();
    #pragma unroll
    for (int j = 0; j < 4; ++j)
        dst[(size_t)(c0 + ty + 8 * j) * R + r0 + tx] = f2bf(t[tx][ty + 8 * j]);
}

// ------------------------------------------------------------------
// fc1 MFMA: out[1+m][n] = gelu(Xb[m] @ W[:,n] + b[n]); 128x64 tile
// ------------------------------------------------------------------
__global__ __launch_bounds__(256) void gemm_fc1(const short* __restrict__ Xb,
                                                const short* __restrict__ Wt,
                                                const float* __restrict__ bias,
                                                float* __restrict__ out)
{
    __shared__ __align__(16) short As[128 * 40];
    __shared__ __align__(16) short Bs[64 * 40];
    const int tid  = threadIdx.x;
    const int row0 = blockIdx.x * 128;
    const int col0 = blockIdx.y * 64;
    const int wave = tid >> 6, lane = tid & 63;
    const int quad = lane >> 4, l16 = lane & 15;
    const int m_off = (wave >> 1) * 64, n_off = (wave & 1) * 32;
    f32x4 acc[4][2] = {};
    for (int k0 = 0; k0 < ID; k0 += 32) {
        #pragma unroll
        for (int seg = 0; seg < 2; ++seg) {
            int lin = tid + 256 * seg;
            int row = lin >> 2, kc = (lin & 3) * 8;
            int gr = row0 + row;
            bf16x8 pa = {};
            if (gr < NPIX) pa = *(const bf16x8*)&Xb[(size_t)gr * ID + k0 + kc];
            *(bf16x8*)&As[row * 40 + kc] = pa;
        }
        {
            int nrow = tid >> 2, kc = (tid & 3) * 8;
            *(bf16x8*)&Bs[nrow * 40 + kc] =
                *(const bf16x8*)&Wt[(size_t)(col0 + nrow) * ID + k0 + kc];
        }
        __syncthreads();
        bf16x8 af[4], bf[2];
        #pragma unroll
        for (int i = 0; i < 4; ++i)
            af[i] = *(const bf16x8*)&As[(m_off + i * 16 + l16) * 40 + quad * 8];
        #pragma unroll
        for (int i = 0; i < 2; ++i)
            bf[i] = *(const bf16x8*)&Bs[(n_off + i * 16 + l16) * 40 + quad * 8];
        #pragma unroll
        for (int mi = 0; mi < 4; ++mi)
            #pragma unroll
            for (int ni = 0; ni < 2; ++ni)
                acc[mi][ni] = __builtin_amdgcn_mfma_f32_16x16x32_bf16(af[mi], bf[ni], acc[mi][ni], 0, 0, 0);
        __syncthreads();
    }
    #pragma unroll
    for (int mi = 0; mi < 4; ++mi) {
        #pragma unroll
        for (int r = 0; r < 4; ++r) {
            int gr = row0 + m_off + mi * 16 + quad * 4 + r;
            if (gr >= NPIX) continue;
            #pragma unroll
            for (int ni = 0; ni < 2; ++ni) {
                int gc = col0 + n_off + ni * 16 + l16;
                float v = acc[mi][ni][r] + bias[gc];
                v = 0.5f * v * (1.f + erff(v * 0.70710678118654752f));
                out[(size_t)(gr + 1) * HD + gc] = v;
            }
        }
    }
}

// ------------------------------------------------------------------
// qkv MFMA: 64x64 tile. grid (308, 3)
// ------------------------------------------------------------------
__global__ __launch_bounds__(256) void gemm_qkv(const short* __restrict__ xpB,
                                                const short* __restrict__ Wt,
                                                float* __restrict__ qh,
                                                float* __restrict__ kh,
                                                float* __restrict__ vh)
{
    __shared__ __align__(16) short As[64 * 40];
    __shared__ __align__(16) short Bs[64 * 40];
    const int tid  = threadIdx.x;
    const int row0 = blockIdx.x * 64;
    const int col0 = blockIdx.y * 64;
    const int wave = tid >> 6, lane = tid & 63;
    const int quad = lane >> 4, l16 = lane & 15;
    const int m_off = (wave >> 1) * 32, n_off = (wave & 1) * 32;
    f32x4 acc[2][2] = {};
    for (int k0 = 0; k0 < HD; k0 += 32) {
        {
            int row = tid >> 2, kc = (tid & 3) * 8;
            *(bf16x8*)&As[row * 40 + kc] =
                *(const bf16x8*)&xpB[(size_t)(row0 + row) * HD + k0 + kc];
            *(bf16x8*)&Bs[row * 40 + kc] =
                *(const bf16x8*)&Wt[(size_t)(col0 + row) * HD + k0 + kc];
        }
        __syncthreads();
        bf16x8 af[2], bf[2];
        #pragma unroll
        for (int i = 0; i < 2; ++i) {
            af[i] = *(const bf16x8*)&As[(m_off + i * 16 + l16) * 40 + quad * 8];
            bf[i] = *(const bf16x8*)&Bs[(n_off + i * 16 + l16) * 40 + quad * 8];
        }
        #pragma unroll
        for (int mi = 0; mi < 2; ++mi)
            #pragma unroll
            for (int ni = 0; ni < 2; ++ni)
                acc[mi][ni] = __builtin_amdgcn_mfma_f32_16x16x32_bf16(af[mi], bf[ni], acc[mi][ni], 0, 0, 0);
        __syncthreads();
    }
    const int which = blockIdx.y;
    float* dst = (which == 0) ? qh : (which == 1) ? kh : vh;
    const float scale = (which == 0) ? 0.35355339059327373f : 1.f;
    #pragma unroll
    for (int mi = 0; mi < 2; ++mi) {
        #pragma unroll
        for (int r = 0; r < 4; ++r) {
            int gr = row0 + m_off + mi * 16 + quad * 4 + r;
            #pragma unroll
            for (int ni = 0; ni < 2; ++ni) {
                int n = n_off + ni * 16 + l16;
                int hh = n >> 3, d = n & 7;
                dst[((size_t)hh * NP + gr) * DH + d] = acc[mi][ni][r] * scale;
            }
        }
    }
}

__global__ void cls_init(const float* __restrict__ cls, float* __restrict__ h)
{
    int t = blockIdx.x * 256 + threadIdx.x;
    if (t < HD) h[t] = cls[t];
}

__global__ void copy512(const float* __restrict__ src, float* __restrict__ dst)
{
    dst[threadIdx.x] = src[threadIdx.x];
}

// ------------------------------------------------------------------
// layernorm rows of h into xp (bf16), first 111 rows zero
// ------------------------------------------------------------------
__global__ void ln_pad(const float* __restrict__ h, const float* __restrict__ g,
                       const float* __restrict__ b, short* __restrict__ xp)
{
    const int row = blockIdx.x;
    const int tid = threadIdx.x;
    short* dst = xp + (size_t)row * HD;
    if (row < PADR) { dst[tid] = 0; dst[tid + 256] = 0; return; }
    const float* src = h + (size_t)(row - PADR) * HD;
    float v0 = src[tid], v1 = src[tid + 256];
    __shared__ float red[256];
    red[tid] = v0 + v1;
    __syncthreads();
    for (int off = 128; off > 0; off >>= 1) {
        if (tid < off) red[tid] += red[tid + off];
        __syncthreads();
    }
    float mu = red[0] * (1.f / HD);
    __syncthreads();
    float d0 = v0 - mu, d1 = v1 - mu;
    red[tid] = d0 * d0 + d1 * d1;
    __syncthreads();
    for (int off = 128; off > 0; off >>= 1) {
        if (tid < off) red[tid] += red[tid + off];
        __syncthreads();
    }
    float inv = rsqrtf(red[0] * (1.f / HD) + 1e-5f);
    dst[tid]       = f2bf(d0 * inv * g[tid] + b[tid]);
    dst[tid + 256] = f2bf(d1 * inv * g[tid + 256] + b[tid + 256]);
}

// ------------------------------------------------------------------
// landmark means
// ------------------------------------------------------------------
__global__ void landmarks(const float* __restrict__ qh, const float* __restrict__ kh,
                          float* __restrict__ ql, float* __restrict__ kl)
{
    int idx = blockIdx.x * 256 + threadIdx.x;
    int sel = idx >> 14;
    int rem = idx & 16383;
    int h = rem >> 11;
    int i = (rem >> 3) & 255;
    int d = rem & 7;
    const float* src = sel ? kh : qh;
    size_t base = ((size_t)h * NP + (size_t)i * 77) * DH + d;
    float s = 0.f;
    for (int j = 0; j < 77; ++j) s += src[base + (size_t)j * DH];
    (sel ? kl : ql)[((size_t)h * NL + i) * DH + d] = s * (1.f / 77.f);
}

// ------------------------------------------------------------------
// attn2 = softmax(q_l @ k_l^T)
// ------------------------------------------------------------------
__global__ void attn2_softmax(const float* __restrict__ ql, const float* __restrict__ kl,
                              float* __restrict__ a)
{
    const int i = blockIdx.x, h = blockIdx.y, j = threadIdx.x;
    __shared__ float sq[8];
    __shared__ float red[256];
    if (j < 8) sq[j] = ql[((size_t)h * NL + i) * DH + j];
    __syncthreads();
    const float* kr = kl + ((size_t)h * NL + j) * DH;
    float s = 0.f;
    #pragma unroll
    for (int d = 0; d < 8; ++d) s += sq[d] * kr[d];
    red[j] = s;
    __syncthreads();
    for (int off = 128; off > 0; off >>= 1) {
        if (j < off) red[j] = fmaxf(red[j], red[j + off]);
        __syncthreads();
    }
    float mx = red[0];
    __syncthreads();
    float e = __expf(s - mx);
    red[j] = e;
    __syncthreads();
    for (int off = 128; off > 0; off >>= 1) {
        if (j < off) red[j] += red[j + off];
        __syncthreads();
    }
    a[((size_t)h * NL + i) * NL + j] = e / red[0];
}

// ------------------------------------------------------------------
// pinv init
// ------------------------------------------------------------------
__global__ void pinv_norms(const float* __restrict__ a, float* __restrict__ part)
{
    const int h = blockIdx.x & 7;
    const int mode = blockIdx.x >> 3;
    const int tid = threadIdx.x;
    const float* ah = a + (size_t)h * NL * NL;
    float s = 0.f;
    if (mode == 0) { for (int j = 0; j < NL; ++j) s += fabsf(ah[tid * NL + j]); }
    else           { for (int i = 0; i < NL; ++i) s += fabsf(ah[i * NL + tid]); }
    __shared__ float red[256];
    red[tid] = s;
    __syncthreads();
    for (int off = 128; off > 0; off >>= 1) {
        if (tid < off) red[tid] = fmaxf(red[tid], red[tid + off]);
        __syncthreads();
    }
    if (tid == 0) part[mode * 8 + h] = red[0];
}

__global__ void z0_init(const float* __restrict__ a, const float* __restrict__ part,
                        float* __restrict__ z)
{
    float s1 = part[0], s2 = part[8];
    #pragma unroll
    for (int h = 1; h < 8; ++h) { s1 = fmaxf(s1, part[h]); s2 = fmaxf(s2, part[8 + h]); }
    float inv = 1.f / (s1 * s2);
    int idx = blockIdx.x * 256 + threadIdx.x;
    int h = idx >> 16;
    int rem = idx & 65535;
    int i = rem >> 8, j = rem & 255;
    z[idx] = a[((size_t)h * NL + j) * NL + i] * inv;
}

// ------------------------------------------------------------------
// batched 256x256x256: D = alpha*(A@B) + beta*A   grid (8,4,8)
// ------------------------------------------------------------------
__global__ void mm256(const float* __restrict__ A, const float* __restrict__ B,
                      float* __restrict__ D, float alpha, float beta)
{
    const int h = blockIdx.z;
    const float* Ah = A + (size_t)h * NL * NL;
    const float* Bh = B + (size_t)h * NL * NL;
    float* Dh = D + (size_t)h * NL * NL;
    __shared__ __align__(16) float As[16][36];
    __shared__ __align__(16) float Bs[16][68];
    const int tid = threadIdx.x;
    const int tx = tid & 15, ty = tid >> 4;
    const int row0 = blockIdx.x * 32;
    const int col0 = blockIdx.y * 64;
    float acc[2][4] = {};
    const int ar = tid >> 3;
    const int ak = (tid & 7) * 2;
    const int bk = tid >> 4;
    const int bj = (tid & 15) * 4;
    for (int k0 = 0; k0 < NL; k0 += 16) {
        float2 av = *(const float2*)&Ah[(size_t)(row0 + ar) * NL + k0 + ak];
        As[ak][ar] = av.x; As[ak + 1][ar] = av.y;
        *(float4*)&Bs[bk][bj] = *(const float4*)&Bh[(size_t)(k0 + bk) * NL + col0 + bj];
        __syncthreads();
        #pragma unroll
        for (int k = 0; k < 16; ++k) {
            float2 a = *(const float2*)&As[k][ty * 2];
            float4 b = *(const float4*)&Bs[k][tx * 4];
            acc[0][0] += a.x * b.x; acc[0][1] += a.x * b.y; acc[0][2] += a.x * b.z; acc[0][3] += a.x * b.w;
            acc[1][0] += a.y * b.x; acc[1][1] += a.y * b.y; acc[1][2] += a.y * b.z; acc[1][3] += a.y * b.w;
        }
        __syncthreads();
    }
    #pragma unroll
    for (int r = 0; r < 2; ++r) {
        int gr = row0 + ty * 2 + r;
        #pragma unroll
        for (int c = 0; c < 4; ++c) {
            int gc = col0 + tx * 4 + c;
            Dh[(size_t)gr * NL + gc] = alpha * acc[r][c] + beta * Ah[(size_t)gr * NL + gc];
        }
    }
}

// ------------------------------------------------------------------
// attn3 @ v: 4 landmarks/block, 4 token-chunks (grid z), partials out
// ------------------------------------------------------------------
__global__ void attn3v(const float* __restrict__ kh, const float* __restrict__ vh,
                       const float* __restrict__ ql, float* __restrict__ part)
{
    const int i0 = blockIdx.x * 4, h = blockIdx.y, ck = blockIdx.z, tid = threadIdx.x;
    __shared__ float sq[4][8];
    __shared__ float wred[4][4][10];
    if (tid < 32) sq[tid >> 3][tid & 7] = ql[((size_t)h * NL + i0 + (tid >> 3)) * DH + (tid & 7)];
    __syncthreads();
    float q[4][8];
    #pragma unroll
    for (int li = 0; li < 4; ++li)
        #pragma unroll
        for (int d = 0; d < 8; ++d) q[li][d] = sq[li][d];
    const float* kb = kh + (size_t)h * NP * DH;
    const float* vb = vh + (size_t)h * NP * DH;
    float m[4] = {-1e30f, -1e30f, -1e30f, -1e30f};
    float den[4] = {};
    float acc[4][8] = {};
    const int tEnd = (ck + 1) * CKT;
    for (int t = ck * CKT + tid; t < tEnd; t += 256) {
        const float4 k0 = *(const float4*)&kb[(size_t)t * 8];
        const float4 k1 = *(const float4*)&kb[(size_t)t * 8 + 4];
        const float4 v0 = *(const float4*)&vb[(size_t)t * 8];
        const float4 v1 = *(const float4*)&vb[(size_t)t * 8 + 4];
        float vv[8] = {v0.x, v0.y, v0.z, v0.w, v1.x, v1.y, v1.z, v1.w};
        float kk[8] = {k0.x, k0.y, k0.z, k0.w, k1.x, k1.y, k1.z, k1.w};
        #pragma unroll
        for (int li = 0; li < 4; ++li) {
            float s = 0.f;
            #pragma unroll
            for (int d = 0; d < 8; ++d) s += q[li][d] * kk[d];
            float nm = fmaxf(m[li], s);
            float sc = __expf(m[li] - nm);
            float e  = __expf(s - nm);
            m[li] = nm;
            den[li] = den[li] * sc + e;
            #pragma unroll
            for (int d = 0; d < 8; ++d) acc[li][d] = acc[li][d] * sc + e * vv[d];
        }
    }
    #pragma unroll
    for (int off = 1; off < 64; off <<= 1) {
        #pragma unroll
        for (int li = 0; li < 4; ++li) {
            float mo = __shfl_xor(m[li], off);
            float dn = __shfl_xor(den[li], off);
            float ao[8];
            #pragma unroll
            for (int d = 0; d < 8; ++d) ao[d] = __shfl_xor(acc[li][d], off);
            float nm = fmaxf(m[li], mo);
            float s1 = __expf(m[li] - nm), s2 = __expf(mo - nm);
            den[li] = den[li] * s1 + dn * s2;
            #pragma unroll
            for (int d = 0; d < 8; ++d) acc[li][d] = acc[li][d] * s1 + ao[d] * s2;
            m[li] = nm;
        }
    }
    const int wave = tid >> 6, lane = tid & 63;
    if (lane == 0) {
        #pragma unroll
        for (int li = 0; li < 4; ++li) {
            wred[wave][li][0] = m[li];
            wred[wave][li][1] = den[li];
            #pragma unroll
            for (int d = 0; d < 8; ++d) wred[wave][li][2 + d] = acc[li][d];
        }
    }
    __syncthreads();
    if (tid < 4) {
        const int li = tid;
        float M = wred[0][li][0], D_ = wred[0][li][1];
        float A[8];
        #pragma unroll
        for (int d = 0; d < 8; ++d) A[d] = wred[0][li][2 + d];
        #pragma unroll
        for (int w = 1; w < 4; ++w) {
            float mo = wred[w][li][0], dn = wred[w][li][1];
            float nm = fmaxf(M, mo);
            float s1 = __expf(M - nm), s2 = __expf(mo - nm);
            D_ = D_ * s1 + dn * s2;
            #pragma unroll
            for (int d = 0; d < 8; ++d) A[d] = A[d] * s1 + wred[w][li][2 + d] * s2;
            M = nm;
        }
        float* p = part + (((size_t)h * NL + i0 + li) * 4 + ck) * 10;
        p[0] = M; p[1] = D_;
        #pragma unroll
        for (int d = 0; d < 8; ++d) p[2 + d] = A[d];
    }
}

// merge 4 chunks -> wbuf[h][i][d];  2048 items
__global__ void attn3v_merge(const float* __restrict__ part, float* __restrict__ wbuf)
{
    int idx = blockIdx.x * 256 + threadIdx.x;   // h*NL+i
    const float* p = part + (size_t)idx * 40;
    float M = p[0], D_ = p[1];
    float A[8];
    #pragma unroll
    for (int d = 0; d < 8; ++d) A[d] = p[2 + d];
    #pragma unroll
    for (int ck = 1; ck < 4; ++ck) {
        const float* q = p + ck * 10;
        float mo = q[0], dn = q[1];
        float nm = fmaxf(M, mo);
        float s1 = __expf(M - nm), s2 = __expf(mo - nm);
        D_ = D_ * s1 + dn * s2;
        #pragma unroll
        for (int d = 0; d < 8; ++d) A[d] = A[d] * s1 + q[2 + d] * s2;
        M = nm;
    }
    float inv = 1.f / D_;
    #pragma unroll
    for (int d = 0; d < 8; ++d) wbuf[(size_t)idx * 8 + d] = A[d] * inv;
}

// ------------------------------------------------------------------
// zw[h][i][d] = sum_j z[h][i][j] * w[h][j][d]
// ------------------------------------------------------------------
__global__ void zw_mul(const float* __restrict__ z, const float* __restrict__ w,
                       float* __restrict__ zw)
{
    int idx = blockIdx.x * 256 + threadIdx.x;
    int h = idx >> 11;
    int rem = idx & 2047;
    int i = rem >> 3, d = rem & 7;
    const float* zr = z + ((size_t)h * NL + i) * NL;
    const float* wb = w + (size_t)h * NL * DH + d;
    float s = 0.f;
    for (int j = 0; j < NL; ++j) s += zr[j] * wb[(size_t)j * DH];
    zw[idx] = s;
}

// ------------------------------------------------------------------
// attn1 fused + dwconv33(v): 2 lanes per token (landmarks split 128/128,
// conv taps split 17/16), merged via shfl_xor(1). grid (154, 8), 256 thr.
// ------------------------------------------------------------------
__global__ void attn1_conv(const float* __restrict__ qh, const float* __restrict__ vh,
                           const float* __restrict__ klg, const float* __restrict__ zwg,
                           const float* __restrict__ rw, float* __restrict__ aout)
{
    const int h = blockIdx.y;
    __shared__ __align__(16) float kl[NL * DH];
    __shared__ __align__(16) float zw[NL * DH];
    const int tid = threadIdx.x;
    for (int q = tid; q < NL * DH; q += 256) {
        kl[q] = klg[(size_t)h * NL * DH + q];
        zw[q] = zwg[(size_t)h * NL * DH + q];
    }
    __syncthreads();
    const int half = tid & 1;
    const int r = blockIdx.x * 128 + (tid >> 1);
    if (r >= NT) return;
    const int t = r + PADR;
    const float* qp = qh + ((size_t)h * NP + t) * DH;
    float4 q0 = *(const float4*)qp;
    float4 q1 = *(const float4*)(qp + 4);
    float m = -1e30f, den = 0.f;
    float4 acc0 = make_float4(0.f, 0.f, 0.f, 0.f);
    float4 acc1 = make_float4(0.f, 0.f, 0.f, 0.f);
    const int iBeg = half * 128, iEnd = iBeg + 128;
    for (int i = iBeg; i < iEnd; ++i) {
        float4 k0 = *(const float4*)&kl[i * 8];
        float4 k1 = *(const float4*)&kl[i * 8 + 4];
        float s = q0.x * k0.x + q0.y * k0.y + q0.z * k0.z + q0.w * k0.w
                + q1.x * k1.x + q1.y * k1.y + q1.z * k1.z + q1.w * k1.w;
        float nm = fmaxf(m, s);
        float sc = __expf(m - nm);
        float e  = __expf(s - nm);
        m = nm;
        den = den * sc + e;
        float4 z0 = *(const float4*)&zw[i * 8];
        float4 z1 = *(const float4*)&zw[i * 8 + 4];
        acc0.x = acc0.x * sc + e * z0.x; acc0.y = acc0.y * sc + e * z0.y;
        acc0.z = acc0.z * sc + e * z0.z; acc0.w = acc0.w * sc + e * z0.w;
        acc1.x = acc1.x * sc + e * z1.x; acc1.y = acc1.y * sc + e * z1.y;
        acc1.z = acc1.z * sc + e * z1.z; acc1.w = acc1.w * sc + e * z1.w;
    }
    // pair merge (lanes 2p / 2p+1 hold halves of the same token)
    {
        float mo = __shfl_xor(m, 1);
        float dn = __shfl_xor(den, 1);
        float a[8] = {acc0.x, acc0.y, acc0.z, acc0.w, acc1.x, acc1.y, acc1.z, acc1.w};
        float ao[8];
        #pragma unroll
        for (int d = 0; d < 8; ++d) ao[d] = __shfl_xor(a[d], 1);
        float nm = fmaxf(m, mo);
        float s1 = __expf(m - nm), s2 = __expf(mo - nm);
        den = den * s1 + dn * s2;
        #pragma unroll
        for (int d = 0; d < 8; ++d) a[d] = a[d] * s1 + ao[d] * s2;
        float inv = 1.f / den;
        acc0 = make_float4(a[0] * inv, a[1] * inv, a[2] * inv, a[3] * inv);
        acc1 = make_float4(a[4] * inv, a[5] * inv, a[6] * inv, a[7] * inv);
    }
    // conv: split taps between the two lanes
    const float* vb = vh + (size_t)h * NP * DH;
    float4 c0 = make_float4(0.f, 0.f, 0.f, 0.f);
    float4 c1 = make_float4(0.f, 0.f, 0.f, 0.f);
    for (int j = half; j < 33; j += 2) {
        int tp = t - 16 + j;
        if (tp >= NP) continue;
        float wv = rw[h * 33 + j];
        float4 v0 = *(const float4*)&vb[(size_t)tp * 8];
        float4 v1 = *(const float4*)&vb[(size_t)tp * 8 + 4];
        F4MAD(c0, wv, v0); F4MAD(c1, wv, v1);
    }
    c0.x += __shfl_xor(c0.x, 1); c0.y += __shfl_xor(c0.y, 1);
    c0.z += __shfl_xor(c0.z, 1); c0.w += __shfl_xor(c0.w, 1);
    c1.x += __shfl_xor(c1.x, 1); c1.y += __shfl_xor(c1.y, 1);
    c1.z += __shfl_xor(c1.z, 1); c1.w += __shfl_xor(c1.w, 1);
    if (half == 0) {
        float* op = aout + (size_t)r * 64 + h * 8;
        *(float4*)op = make_float4(acc0.x + c0.x, acc0.y + c0.y, acc0.z + c0.z, acc0.w + c0.w);
        *(float4*)(op + 4) = make_float4(acc1.x + c1.x, acc1.y + c1.y, acc1.z + c1.z, acc1.w + c1.w);
    }
}

// ------------------------------------------------------------------
// out-proj + residual: 16 rows/block
// ------------------------------------------------------------------
__global__ void outproj(const float* __restrict__ aout, const float* __restrict__ W,
                        const float* __restrict__ bias, float* __restrict__ h)
{
    const int r0 = blockIdx.x * 16;
    const int tid = threadIdx.x;   // 512
    __shared__ float ao[16][64];
    #pragma unroll
    for (int s = 0; s < 2; ++s) {
        int idx = tid + s * 512;
        int rr = idx >> 6, kk = idx & 63;
        int gr = r0 + rr;
        ao[rr][kk] = (gr < NT) ? aout[(size_t)gr * 64 + kk] : 0.f;
    }
    __syncthreads();
    float acc[16] = {};
    for (int k = 0; k < 64; ++k) {
        float wv = W[(size_t)k * HD + tid];
        #pragma unroll
        for (int r = 0; r < 16; ++r) acc[r] += ao[r][k] * wv;
    }
    float bv = bias[tid];
    #pragma unroll
    for (int r = 0; r < 16; ++r) {
        int gr = r0 + r;
        if (gr < NT) h[(size_t)gr * HD + tid] += acc[r] + bv;
    }
}

// ------------------------------------------------------------------
// PPEG
// ------------------------------------------------------------------
__global__ void ppeg_wprep(const float* __restrict__ w7, const float* __restrict__ b7,
                           const float* __restrict__ w5, const float* __restrict__ b5,
                           const float* __restrict__ w3, const float* __restrict__ b3,
                           float* __restrict__ wc, float* __restrict__ bsum)
{
    int idx = blockIdx.x * 256 + threadIdx.x;
    if (idx < HD * 49) {
        int c = idx / 49, t = idx - c * 49;
        int dy = t / 7 - 3, dx = t % 7 - 3;
        float v = w7[idx];
        if (dy >= -2 && dy <= 2 && dx >= -2 && dx <= 2) v += w5[c * 25 + (dy + 2) * 5 + (dx + 2)];
        if (dy >= -1 && dy <= 1 && dx >= -1 && dx <= 1) v += w3[c * 9 + (dy + 1) * 3 + (dx + 1)];
        if (t == 24) v += 1.f;
        wc[idx] = v;
    } else if (idx < HD * 49 + HD) {
        int c = idx - HD * 49;
        bsum[c] = b7[c] + b5[c] + b3[c];
    }
}

__global__ void ppeg_t1(const float* __restrict__ hin, float* __restrict__ plan, int ch0)
{
    __shared__ float tile[32][33];
    const int tx = threadIdx.x & 31, ty = threadIdx.x >> 5;
    const int p0 = blockIdx.x * 32;
    const int c0 = ch0 + blockIdx.y * 32;
    #pragma unroll
    for (int j = 0; j < 4; ++j) {
        int p = p0 + ty + j * 8;
        tile[ty + j * 8][tx] = (p < NPIX) ? hin[(size_t)(1 + p) * HD + c0 + tx] : 0.f;
    }
    __syncthreads();
    #pragma unroll
    for (int j = 0; j < 4; ++j) {
        int p = p0 + tx;
        int cc = ty + j * 8;
        if (p < NPIX) plan[(size_t)(blockIdx.y * 32 + cc) * NPIX + p] = tile[tx][cc];
    }
}

__global__ __launch_bounds__(256) void ppeg_conv(const float* __restrict__ plan,
                                                 const float* __restrict__ wc,
                                                 float* __restrict__ plan2, int ch0)
{
    __shared__ __align__(16) float img[41 * PW];
    const int tid = threadIdx.x;
    const int cl = blockIdx.x;
    const int yq = blockIdx.y;
    for (int i = tid; i < 41 * PW; i += 256) img[i] = 0.f;
    __syncthreads();
    const float* src = plan + (size_t)cl * NPIX;
    for (int i = tid; i < 41 * SIDE; i += 256) {
        int ly = i / SIDE, x = i - ly * SIDE;
        int y = yq * 35 - 3 + ly;
        if (y >= 0 && y < SIDE) img[ly * PW + x + 3] = src[y * SIDE + x];
    }
    const float* w = wc + (size_t)(ch0 + cl) * 49;
    float wr[49];
    #pragma unroll
    for (int t = 0; t < 49; ++t) wr[t] = w[t];
    __syncthreads();
    float* dst = plan2 + (size_t)cl * NPIX;
    for (int g = tid; g < 35 * 35; g += 256) {
        int yl = g / 35, x0 = (g - yl * 35) * 4;
        float acc0 = 0.f, acc1 = 0.f, acc2 = 0.f, acc3 = 0.f;
        #pragma unroll
        for (int a = 0; a < 7; ++a) {
            const float* row = &img[(yl + a) * PW + x0];
            float4 A = *(const float4*)(row);
            float4 B = *(const float4*)(row + 4);
            float4 C = *(const float4*)(row + 8);
            float e0 = A.x, e1 = A.y, e2 = A.z, e3 = A.w;
            float e4 = B.x, e5 = B.y, e6 = B.z, e7 = B.w;
            float e8 = C.x, e9 = C.y;
            const float w0 = wr[a*7+0], w1 = wr[a*7+1], w2 = wr[a*7+2], w3v = wr[a*7+3];
            const float w4 = wr[a*7+4], w5v = wr[a*7+5], w6 = wr[a*7+6];
            acc0 += w0*e0 + w1*e1 + w2*e2 + w3v*e3 + w4*e4 + w5v*e5 + w6*e6;
            acc1 += w0*e1 + w1*e2 + w2*e3 + w3v*e4 + w4*e5 + w5v*e6 + w6*e7;
            acc2 += w0*e2 + w1*e3 + w2*e4 + w3v*e5 + w4*e6 + w5v*e7 + w6*e8;
            acc3 += w0*e3 + w1*e4 + w2*e5 + w3v*e6 + w4*e7 + w5v*e8 + w6*e9;
        }
        *(float4*)&dst[(yq * 35 + yl) * SIDE + x0] = make_float4(acc0, acc1, acc2, acc3);
    }
}

__global__ void ppeg_t2(const float* __restrict__ plan2, const float* __restrict__ bsum,
                        float* __restrict__ hout, int ch0)
{
    __shared__ float tile[32][33];
    const int tx = threadIdx.x & 31, ty = threadIdx.x >> 5;
    const int p0 = blockIdx.x * 32;
    #pragma unroll
    for (int j = 0; j < 4; ++j) {
        int p = p0 + tx;
        int cc = ty + j * 8;
        tile[tx][cc] = (p < NPIX) ? plan2[(size_t)(blockIdx.y * 32 + cc) * NPIX + p] : 0.f;
    }
    __syncthreads();
    const int c0 = ch0 + blockIdx.y * 32;
    float bv = bsum[c0 + tx];
    #pragma unroll
    for (int j = 0; j < 4; ++j) {
        int p = p0 + ty + j * 8;
        if (p < NPIX) hout[(size_t)(1 + p) * HD + c0 + tx] = tile[ty + j * 8][tx] + bv;
    }
}

// ------------------------------------------------------------------
// final layernorm of row 0
// ------------------------------------------------------------------
__global__ void final_ln(const float* __restrict__ h, const float* __restrict__ g,
                         const float* __restrict__ b, float* __restrict__ out)
{
    const int tid = threadIdx.x;
    float v0 = h[tid], v1 = h[tid + 256];
    __shared__ float red[256];
    red[tid] = v0 + v1;
    __syncthreads();
    for (int off = 128; off > 0; off >>= 1) {
        if (tid < off) red[tid] += red[tid + off];
        __syncthreads();
    }
    float mu = red[0] * (1.f / HD);
    __syncthreads();
    float d0 = v0 - mu, d1 = v1 - mu;
    red[tid] = d0 * d0 + d1 * d1;
    __syncthreads();
    for (int off = 128; off > 0; off >>= 1) {
        if (tid < off) red[tid] += red[tid + off];
        __syncthreads();
    }
    float inv = rsqrtf(red[0] * (1.f / HD) + 1e-5f);
    out[tid]       = d0 * inv * g[tid] + b[tid];
    out[tid + 256] = d1 * inv * g[tid + 256] + b[tid + 256];
}

} // namespace

extern "C" void kernel_launch(void* const* d_in, const int* in_sizes, int n_in,
                              void* d_out, int out_size, void* d_ws, size_t ws_size,
                              hipStream_t stream)
{
    const float* x      = (const float*)d_in[0];
    const float* fc1_w  = (const float*)d_in[1];
    const float* fc1_b  = (const float*)d_in[2];
    const float* cls    = (const float*)d_in[3];
    const float* l1_g   = (const float*)d_in[4];
    const float* l1_bb  = (const float*)d_in[5];
    const float* l1_qkv = (const float*)d_in[6];
    const float* l1_ow  = (const float*)d_in[7];
    const float* l1_ob  = (const float*)d_in[8];
    const float* l1_rw  = (const float*)d_in[9];
    const float* l2_g   = (const float*)d_in[10];
    const float* l2_bb  = (const float*)d_in[11];
    const float* l2_qkv = (const float*)d_in[12];
    const float* l2_ow  = (const float*)d_in[13];
    const float* l2_ob  = (const float*)d_in[14];
    const float* l2_rw  = (const float*)d_in[15];
    const float* p7w    = (const float*)d_in[16];
    const float* p7b    = (const float*)d_in[17];
    const float* p5w    = (const float*)d_in[18];
    const float* p5b    = (const float*)d_in[19];
    const float* p3w    = (const float*)d_in[20];
    const float* p3b    = (const float*)d_in[21];
    const float* ng     = (const float*)d_in[22];
    const float* nb     = (const float*)d_in[23];
    float* out = (float*)d_out;

    char* ws = (char*)d_ws;
    size_t off = 0;
    auto alloc = [&](size_t bytes) {
        char* p = ws + off;
        off += (bytes + 255) & ~(size_t)255;
        return (void*)p;
    };
    float* bufA = (float*)alloc((size_t)NP * HD * 4);
    float* bufB = (float*)alloc((size_t)NP * HD * 4);
    float* qh   = (float*)alloc((size_t)NH * NP * DH * 4);
    float* kh   = (float*)alloc((size_t)NH * NP * DH * 4);
    float* vh   = (float*)alloc((size_t)NH * NP * DH * 4);
    float* aout = (float*)alloc((size_t)NP * 64 * 4);
    float* ql   = (float*)alloc((size_t)NH * NL * DH * 4);
    float* klm  = (float*)alloc((size_t)NH * NL * DH * 4);
    float* wbuf = (float*)alloc((size_t)NH * NL * DH * 4);
    float* zwb  = (float*)alloc((size_t)NH * NL * DH * 4);
    float* a2   = (float*)alloc((size_t)NH * NL * NL * 4);
    float* zb0  = (float*)alloc((size_t)NH * NL * NL * 4);
    float* zb1  = (float*)alloc((size_t)NH * NL * NL * 4);
    float* azb  = (float*)alloc((size_t)NH * NL * NL * 4);
    float* tb   = (float*)alloc((size_t)NH * NL * NL * 4);
    float* ub   = (float*)alloc((size_t)NH * NL * NL * 4);
    float* part = (float*)alloc(256);
    float* a3p  = (float*)alloc((size_t)NH * NL * 4 * 10 * 4);   // attn3v partials
    float* plan  = (float*)alloc((size_t)CCH * NPIX * 4);
    float* plan2 = (float*)alloc((size_t)CCH * NPIX * 4);
    float* wcomb = (float*)alloc((size_t)HD * 49 * 4);
    float* bsum  = (float*)alloc((size_t)HD * 4);
    short* wt1   = (short*)alloc((size_t)HD * ID * 2);
    short* wtq   = (short*)alloc((size_t)192 * HD * 2);
    short* xb    = (short*)alloc((size_t)NPIX * ID * 2);
    short* xpB   = (short*)alloc((size_t)NP * HD * 2);
    (void)ws_size; (void)in_sizes; (void)n_in; (void)out_size;

    castX<<<(NPIX * ID / 8) / 256, 256, 0, stream>>>(x, xb);
    castT<<<dim3(HD / 32, ID / 32), 256, 0, stream>>>(fc1_w, wt1, ID, HD);
    gemm_fc1<<<dim3(154, 8), 256, 0, stream>>>(xb, wt1, fc1_b, bufA);
    cls_init<<<2, 256, 0, stream>>>(cls, bufA);

    auto attention = [&](float* hbuf, const float* lg, const float* lb,
                         const float* qkvw, const float* ow, const float* ob,
                         const float* rw) {
        ln_pad<<<NP, 256, 0, stream>>>(hbuf, lg, lb, xpB);
        castT<<<dim3(192 / 32, HD / 32), 256, 0, stream>>>(qkvw, wtq, HD, 192);
        gemm_qkv<<<dim3(NP / 64, 3), 256, 0, stream>>>(xpB, wtq, qh, kh, vh);
        landmarks<<<128, 256, 0, stream>>>(qh, kh, ql, klm);
        attn2_softmax<<<dim3(NL, NH), 256, 0, stream>>>(ql, klm, a2);
        pinv_norms<<<16, 256, 0, stream>>>(a2, part);
        z0_init<<<2048, 256, 0, stream>>>(a2, part, zb0);
        float* zc = zb0;
        float* zn = zb1;
        for (int it = 0; it < 6; ++it) {
            mm256<<<dim3(8, 4, 8), 256, 0, stream>>>(a2, zc, azb, 1.f, 0.f);
            mm256<<<dim3(8, 4, 8), 256, 0, stream>>>(azb, azb, tb, -1.f, 7.f);
            mm256<<<dim3(8, 4, 8), 256, 0, stream>>>(azb, tb, ub, -1.f, 15.f);
            mm256<<<dim3(8, 4, 8), 256, 0, stream>>>(zc, ub, zn, -0.25f, 3.25f);
            float* tmp = zc; zc = zn; zn = tmp;
        }
        attn3v<<<dim3(NL / 4, NH, 4), 256, 0, stream>>>(kh, vh, ql, a3p);
        attn3v_merge<<<8, 256, 0, stream>>>(a3p, wbuf);
        zw_mul<<<64, 256, 0, stream>>>(zc, wbuf, zwb);
        attn1_conv<<<dim3(154, NH), 256, 0, stream>>>(qh, vh, klm, zwb, rw, aout);
        outproj<<<(NT + 15) / 16, 512, 0, stream>>>(aout, ow, ob, hbuf);
    };

    attention(bufA, l1_g, l1_bb, l1_qkv, l1_ow, l1_ob, l1_rw);

    ppeg_wprep<<<(HD * 49 + HD + 255) / 256, 256, 0, stream>>>(p7w, p7b, p5w, p5b, p3w, p3b,
                                                               wcomb, bsum);
    copy512<<<1, 512, 0, stream>>>(bufA, bufB);
    constexpr int PTILES = (NPIX + 31) / 32;
    for (int ch0 = 0; ch0 < HD; ch0 += CCH) {
        ppeg_t1<<<dim3(PTILES, CCH / 32), 256, 0, stream>>>(bufA, plan, ch0);
        ppeg_conv<<<dim3(CCH, 4), 256, 0, stream>>>(plan, wcomb, plan2, ch0);
        ppeg_t2<<<dim3(PTILES, CCH / 32), 256, 0, stream>>>(plan2, bsum, bufB, ch0);
    }

    attention(bufB, l2_g, l2_bb, l2_qkv, l2_ow, l2_ob, l2_rw);
    final_ln<<<1, 256, 0, stream>>>(bufB, ng, nb, out);
}

// Round 9
// 1429.164 us; speedup vs baseline: 2.8825x; 1.0206x over previous
//
#include <hip/hip_runtime.h>

namespace {

constexpr int NP   = 19712;   // padded tokens (Nystrom)
constexpr int NT   = 19601;   // tokens incl cls
constexpr int NPIX = 19600;   // feature tokens (140x140)
constexpr int HD   = 512;     // hidden dim
constexpr int ID   = 1024;    // input dim
constexpr int NH   = 8;       // heads
constexpr int DH   = 8;       // dim per head
constexpr int NL   = 256;     // landmarks
constexpr int PADR = 111;     // left zero-pad rows
constexpr int SIDE = 140;
constexpr int CCH  = 128;     // ppeg channel chunk
constexpr int PW   = 148;     // padded image row stride (floats)
constexpr int CKT  = NP / 4;  // attn3v token chunk = 4928

typedef __attribute__((ext_vector_type(8))) short bf16x8;
typedef __attribute__((ext_vector_type(4))) float f32x4;

#define F4MAD(a, s, v) { (a).x += (s)*(v).x; (a).y += (s)*(v).y; (a).z += (s)*(v).z; (a).w += (s)*(v).w; }
#define F4SCALE(a, s)  { (a).x *= (s); (a).y *= (s); (a).z *= (s); (a).w *= (s); }

__device__ inline short f2bf(float f) {
    union { float f; unsigned u; } v; v.f = f;
    unsigned r = v.u + 0x7fffu + ((v.u >> 16) & 1u);
    return (short)(r >> 16);
}

// ------------------------------------------------------------------
// cast X fp32 -> bf16 elementwise
// ------------------------------------------------------------------
__global__ void castX(const float* __restrict__ src, short* __restrict__ dst)
{
    size_t c = (size_t)blockIdx.x * 256 + threadIdx.x;
    const float4 x0 = *(const float4*)&src[c * 8];
    const float4 x1 = *(const float4*)&src[c * 8 + 4];
    bf16x8 p;
    p[0] = f2bf(x0.x); p[1] = f2bf(x0.y); p[2] = f2bf(x0.z); p[3] = f2bf(x0.w);
    p[4] = f2bf(x1.x); p[5] = f2bf(x1.y); p[6] = f2bf(x1.z); p[7] = f2bf(x1.w);
    *(bf16x8*)&dst[c * 8] = p;
}

// ------------------------------------------------------------------
// cast+transpose: dst[c][r] = bf16(src[r][c]); grid (C/32, R/32)
// ------------------------------------------------------------------
__global__ void castT(const float* __restrict__ src, short* __restrict__ dst, int R, int C)
{
    __shared__ float t[32][33];
    const int tx = threadIdx.x & 31, ty = threadIdx.x >> 5;
    const int c0 = blockIdx.x * 32, r0 = blockIdx.y * 32;
    #pragma unroll
    for (int j = 0; j < 4; ++j)
        t[ty + 8 * j][tx] = src[(size_t)(r0 + ty + 8 * j) * C + c0 + tx];
    __syncthreads();
    #pragma unroll
    for (int j = 0; j < 4; ++j)
        dst[(size_t)(c0 + ty + 8 * j) * R + r0 + tx] = f2bf(t[tx][ty + 8 * j]);
}

// ------------------------------------------------------------------
// fc1 MFMA: out[1+m][n] = gelu(Xb[m] @ W[:,n] + b[n]); 128x64 tile
// ------------------------------------------------------------------
__global__ __launch_bounds__(256) void gemm_fc1(const short* __restrict__ Xb,
                                                const short* __restrict__ Wt,
                                                const float* __restrict__ bias,
                                                float* __restrict__ out)
{
    __shared__ __align__(16) short As[128 * 40];
    __shared__ __align__(16) short Bs[64 * 40];
    const int tid  = threadIdx.x;
    const int row0 = blockIdx.x * 128;
    const int col0 = blockIdx.y * 64;
    const int wave = tid >> 6, lane = tid & 63;
    const int quad = lane >> 4, l16 = lane & 15;
    const int m_off = (wave >> 1) * 64, n_off = (wave & 1) * 32;
    f32x4 acc[4][2] = {};
    for (int k0 = 0; k0 < ID; k0 += 32) {
        #pragma unroll
        for (int seg = 0; seg < 2; ++seg) {
            int lin = tid + 256 * seg;
            int row = lin >> 2, kc = (lin & 3) * 8;
            int gr = row0 + row;
            bf16x8 pa = {};
            if (gr < NPIX) pa = *(const bf16x8*)&Xb[(size_t)gr * ID + k0 + kc];
            *(bf16x8*)&As[row * 40 + kc] = pa;
        }
        {
            int nrow = tid >> 2, kc = (tid & 3) * 8;
            *(bf16x8*)&Bs[nrow * 40 + kc] =
                *(const bf16x8*)&Wt[(size_t)(col0 + nrow) * ID + k0 + kc];
        }
        __syncthreads();
        bf16x8 af[4], bf[2];
        #pragma unroll
        for (int i = 0; i < 4; ++i)
            af[i] = *(const bf16x8*)&As[(m_off + i * 16 + l16) * 40 + quad * 8];
        #pragma unroll
        for (int i = 0; i < 2; ++i)
            bf[i] = *(const bf16x8*)&Bs[(n_off + i * 16 + l16) * 40 + quad * 8];
        #pragma unroll
        for (int mi = 0; mi < 4; ++mi)
            #pragma unroll
            for (int ni = 0; ni < 2; ++ni)
                acc[mi][ni] = __builtin_amdgcn_mfma_f32_16x16x32_bf16(af[mi], bf[ni], acc[mi][ni], 0, 0, 0);
        __syncthreads();
    }
    #pragma unroll
    for (int mi = 0; mi < 4; ++mi) {
        #pragma unroll
        for (int r = 0; r < 4; ++r) {
            int gr = row0 + m_off + mi * 16 + quad * 4 + r;
            if (gr >= NPIX) continue;
            #pragma unroll
            for (int ni = 0; ni < 2; ++ni) {
                int gc = col0 + n_off + ni * 16 + l16;
                float v = acc[mi][ni][r] + bias[gc];
                v = 0.5f * v * (1.f + erff(v * 0.70710678118654752f));
                out[(size_t)(gr + 1) * HD + gc] = v;
            }
        }
    }
}

// ------------------------------------------------------------------
// qkv MFMA: 64x64 tile. grid (308, 3)
// ------------------------------------------------------------------
__global__ __launch_bounds__(256) void gemm_qkv(const short* __restrict__ xpB,
                                                const short* __restrict__ Wt,
                                                float* __restrict__ qh,
                                                float* __restrict__ kh,
                                                float* __restrict__ vh)
{
    __shared__ __align__(16) short As[64 * 40];
    __shared__ __align__(16) short Bs[64 * 40];
    const int tid  = threadIdx.x;
    const int row0 = blockIdx.x * 64;
    const int col0 = blockIdx.y * 64;
    const int wave = tid >> 6, lane = tid & 63;
    const int quad = lane >> 4, l16 = lane & 15;
    const int m_off = (wave >> 1) * 32, n_off = (wave & 1) * 32;
    f32x4 acc[2][2] = {};
    for (int k0 = 0; k0 < HD; k0 += 32) {
        {
            int row = tid >> 2, kc = (tid & 3) * 8;
            *(bf16x8*)&As[row * 40 + kc] =
                *(const bf16x8*)&xpB[(size_t)(row0 + row) * HD + k0 + kc];
            *(bf16x8*)&Bs[row * 40 + kc] =
                *(const bf16x8*)&Wt[(size_t)(col0 + row) * HD + k0 + kc];
        }
        __syncthreads();
        bf16x8 af[2], bf[2];
        #pragma unroll
        for (int i = 0; i < 2; ++i) {
            af[i] = *(const bf16x8*)&As[(m_off + i * 16 + l16) * 40 + quad * 8];
            bf[i] = *(const bf16x8*)&Bs[(n_off + i * 16 + l16) * 40 + quad * 8];
        }
        #pragma unroll
        for (int mi = 0; mi < 2; ++mi)
            #pragma unroll
            for (int ni = 0; ni < 2; ++ni)
                acc[mi][ni] = __builtin_amdgcn_mfma_f32_16x16x32_bf16(af[mi], bf[ni], acc[mi][ni], 0, 0, 0);
        __syncthreads();
    }
    const int which = blockIdx.y;
    float* dst = (which == 0) ? qh : (which == 1) ? kh : vh;
    const float scale = (which == 0) ? 0.35355339059327373f : 1.f;
    #pragma unroll
    for (int mi = 0; mi < 2; ++mi) {
        #pragma unroll
        for (int r = 0; r < 4; ++r) {
            int gr = row0 + m_off + mi * 16 + quad * 4 + r;
            #pragma unroll
            for (int ni = 0; ni < 2; ++ni) {
                int n = n_off + ni * 16 + l16;
                int hh = n >> 3, d = n & 7;
                dst[((size_t)hh * NP + gr) * DH + d] = acc[mi][ni][r] * scale;
            }
        }
    }
}

__global__ void cls_init(const float* __restrict__ cls, float* __restrict__ h)
{
    int t = blockIdx.x * 256 + threadIdx.x;
    if (t < HD) h[t] = cls[t];
}

__global__ void copy512(const float* __restrict__ src, float* __restrict__ dst)
{
    dst[threadIdx.x] = src[threadIdx.x];
}

// ------------------------------------------------------------------
// layernorm rows of h into xp (bf16), first 111 rows zero
// ------------------------------------------------------------------
__global__ void ln_pad(const float* __restrict__ h, const float* __restrict__ g,
                       const float* __restrict__ b, short* __restrict__ xp)
{
    const int row = blockIdx.x;
    const int tid = threadIdx.x;
    short* dst = xp + (size_t)row * HD;
    if (row < PADR) { dst[tid] = 0; dst[tid + 256] = 0; return; }
    const float* src = h + (size_t)(row - PADR) * HD;
    float v0 = src[tid], v1 = src[tid + 256];
    __shared__ float red[256];
    red[tid] = v0 + v1;
    __syncthreads();
    for (int off = 128; off > 0; off >>= 1) {
        if (tid < off) red[tid] += red[tid + off];
        __syncthreads();
    }
    float mu = red[0] * (1.f / HD);
    __syncthreads();
    float d0 = v0 - mu, d1 = v1 - mu;
    red[tid] = d0 * d0 + d1 * d1;
    __syncthreads();
    for (int off = 128; off > 0; off >>= 1) {
        if (tid < off) red[tid] += red[tid + off];
        __syncthreads();
    }
    float inv = rsqrtf(red[0] * (1.f / HD) + 1e-5f);
    dst[tid]       = f2bf(d0 * inv * g[tid] + b[tid]);
    dst[tid + 256] = f2bf(d1 * inv * g[tid + 256] + b[tid + 256]);
}

// ------------------------------------------------------------------
// landmark means
// ------------------------------------------------------------------
__global__ void landmarks(const float* __restrict__ qh, const float* __restrict__ kh,
                          float* __restrict__ ql, float* __restrict__ kl)
{
    int idx = blockIdx.x * 256 + threadIdx.x;
    int sel = idx >> 14;
    int rem = idx & 16383;
    int h = rem >> 11;
    int i = (rem >> 3) & 255;
    int d = rem & 7;
    const float* src = sel ? kh : qh;
    size_t base = ((size_t)h * NP + (size_t)i * 77) * DH + d;
    float s = 0.f;
    for (int j = 0; j < 77; ++j) s += src[base + (size_t)j * DH];
    (sel ? kl : ql)[((size_t)h * NL + i) * DH + d] = s * (1.f / 77.f);
}

// ------------------------------------------------------------------
// attn2 = softmax(q_l @ k_l^T); scores are O(1) -> no max subtraction
// ------------------------------------------------------------------
__global__ void attn2_softmax(const float* __restrict__ ql, const float* __restrict__ kl,
                              float* __restrict__ a)
{
    const int i = blockIdx.x, h = blockIdx.y, j = threadIdx.x;
    __shared__ float sq[8];
    __shared__ float red[256];
    if (j < 8) sq[j] = ql[((size_t)h * NL + i) * DH + j];
    __syncthreads();
    const float* kr = kl + ((size_t)h * NL + j) * DH;
    float s = 0.f;
    #pragma unroll
    for (int d = 0; d < 8; ++d) s += sq[d] * kr[d];
    float e = __expf(s);
    red[j] = e;
    __syncthreads();
    for (int off = 128; off > 0; off >>= 1) {
        if (j < off) red[j] += red[j + off];
        __syncthreads();
    }
    a[((size_t)h * NL + i) * NL + j] = e / red[0];
}

// ------------------------------------------------------------------
// pinv init
// ------------------------------------------------------------------
__global__ void pinv_norms(const float* __restrict__ a, float* __restrict__ part)
{
    const int h = blockIdx.x & 7;
    const int mode = blockIdx.x >> 3;
    const int tid = threadIdx.x;
    const float* ah = a + (size_t)h * NL * NL;
    float s = 0.f;
    if (mode == 0) { for (int j = 0; j < NL; ++j) s += fabsf(ah[tid * NL + j]); }
    else           { for (int i = 0; i < NL; ++i) s += fabsf(ah[i * NL + tid]); }
    __shared__ float red[256];
    red[tid] = s;
    __syncthreads();
    for (int off = 128; off > 0; off >>= 1) {
        if (tid < off) red[tid] = fmaxf(red[tid], red[tid + off]);
        __syncthreads();
    }
    if (tid == 0) part[mode * 8 + h] = red[0];
}

__global__ void z0_init(const float* __restrict__ a, const float* __restrict__ part,
                        float* __restrict__ z)
{
    float s1 = part[0], s2 = part[8];
    #pragma unroll
    for (int h = 1; h < 8; ++h) { s1 = fmaxf(s1, part[h]); s2 = fmaxf(s2, part[8 + h]); }
    float inv = 1.f / (s1 * s2);
    int idx = blockIdx.x * 256 + threadIdx.x;
    int h = idx >> 16;
    int rem = idx & 65535;
    int i = rem >> 8, j = rem & 255;
    z[idx] = a[((size_t)h * NL + j) * NL + i] * inv;
}

// ------------------------------------------------------------------
// batched 256x256x256: D = alpha*(A@B) + beta*A   grid (8,4,8)
// ------------------------------------------------------------------
__global__ void mm256(const float* __restrict__ A, const float* __restrict__ B,
                      float* __restrict__ D, float alpha, float beta)
{
    const int h = blockIdx.z;
    const float* Ah = A + (size_t)h * NL * NL;
    const float* Bh = B + (size_t)h * NL * NL;
    float* Dh = D + (size_t)h * NL * NL;
    __shared__ __align__(16) float As[16][36];
    __shared__ __align__(16) float Bs[16][68];
    const int tid = threadIdx.x;
    const int tx = tid & 15, ty = tid >> 4;
    const int row0 = blockIdx.x * 32;
    const int col0 = blockIdx.y * 64;
    float acc[2][4] = {};
    const int ar = tid >> 3;
    const int ak = (tid & 7) * 2;
    const int bk = tid >> 4;
    const int bj = (tid & 15) * 4;
    for (int k0 = 0; k0 < NL; k0 += 16) {
        float2 av = *(const float2*)&Ah[(size_t)(row0 + ar) * NL + k0 + ak];
        As[ak][ar] = av.x; As[ak + 1][ar] = av.y;
        *(float4*)&Bs[bk][bj] = *(const float4*)&Bh[(size_t)(k0 + bk) * NL + col0 + bj];
        __syncthreads();
        #pragma unroll
        for (int k = 0; k < 16; ++k) {
            float2 a = *(const float2*)&As[k][ty * 2];
            float4 b = *(const float4*)&Bs[k][tx * 4];
            acc[0][0] += a.x * b.x; acc[0][1] += a.x * b.y; acc[0][2] += a.x * b.z; acc[0][3] += a.x * b.w;
            acc[1][0] += a.y * b.x; acc[1][1] += a.y * b.y; acc[1][2] += a.y * b.z; acc[1][3] += a.y * b.w;
        }
        __syncthreads();
    }
    #pragma unroll
    for (int r = 0; r < 2; ++r) {
        int gr = row0 + ty * 2 + r;
        #pragma unroll
        for (int c = 0; c < 4; ++c) {
            int gc = col0 + tx * 4 + c;
            Dh[(size_t)gr * NL + gc] = alpha * acc[r][c] + beta * Ah[(size_t)gr * NL + gc];
        }
    }
}

// ------------------------------------------------------------------
// attn3 @ v: no-max softmax (scores O(1)); 4 landmarks/block, 4 chunks
// ------------------------------------------------------------------
__global__ void attn3v(const float* __restrict__ kh, const float* __restrict__ vh,
                       const float* __restrict__ ql, float* __restrict__ part)
{
    const int i0 = blockIdx.x * 4, h = blockIdx.y, ck = blockIdx.z, tid = threadIdx.x;
    __shared__ float sq[4][8];
    __shared__ float wred[4][4][9];
    if (tid < 32) sq[tid >> 3][tid & 7] = ql[((size_t)h * NL + i0 + (tid >> 3)) * DH + (tid & 7)];
    __syncthreads();
    float q[4][8];
    #pragma unroll
    for (int li = 0; li < 4; ++li)
        #pragma unroll
        for (int d = 0; d < 8; ++d) q[li][d] = sq[li][d];
    const float* kb = kh + (size_t)h * NP * DH;
    const float* vb = vh + (size_t)h * NP * DH;
    float den[4] = {};
    float acc[4][8] = {};
    const int tEnd = (ck + 1) * CKT;
    for (int t = ck * CKT + tid; t < tEnd; t += 256) {
        const float4 k0 = *(const float4*)&kb[(size_t)t * 8];
        const float4 k1 = *(const float4*)&kb[(size_t)t * 8 + 4];
        const float4 v0 = *(const float4*)&vb[(size_t)t * 8];
        const float4 v1 = *(const float4*)&vb[(size_t)t * 8 + 4];
        float vv[8] = {v0.x, v0.y, v0.z, v0.w, v1.x, v1.y, v1.z, v1.w};
        float kk[8] = {k0.x, k0.y, k0.z, k0.w, k1.x, k1.y, k1.z, k1.w};
        #pragma unroll
        for (int li = 0; li < 4; ++li) {
            float s = 0.f;
            #pragma unroll
            for (int d = 0; d < 8; ++d) s += q[li][d] * kk[d];
            float e = __expf(s);
            den[li] += e;
            #pragma unroll
            for (int d = 0; d < 8; ++d) acc[li][d] += e * vv[d];
        }
    }
    #pragma unroll
    for (int off = 1; off < 64; off <<= 1) {
        #pragma unroll
        for (int li = 0; li < 4; ++li) {
            den[li] += __shfl_xor(den[li], off);
            #pragma unroll
            for (int d = 0; d < 8; ++d) acc[li][d] += __shfl_xor(acc[li][d], off);
        }
    }
    const int wave = tid >> 6, lane = tid & 63;
    if (lane == 0) {
        #pragma unroll
        for (int li = 0; li < 4; ++li) {
            wred[wave][li][0] = den[li];
            #pragma unroll
            for (int d = 0; d < 8; ++d) wred[wave][li][1 + d] = acc[li][d];
        }
    }
    __syncthreads();
    if (tid < 4) {
        const int li = tid;
        float D_ = 0.f;
        float A[8] = {};
        #pragma unroll
        for (int w = 0; w < 4; ++w) {
            D_ += wred[w][li][0];
            #pragma unroll
            for (int d = 0; d < 8; ++d) A[d] += wred[w][li][1 + d];
        }
        float* p = part + (((size_t)h * NL + i0 + li) * 4 + ck) * 10;
        p[0] = D_;
        #pragma unroll
        for (int d = 0; d < 8; ++d) p[1 + d] = A[d];
    }
}

// merge 4 chunks -> wbuf[h][i][d];  2048 items
__global__ void attn3v_merge(const float* __restrict__ part, float* __restrict__ wbuf)
{
    int idx = blockIdx.x * 256 + threadIdx.x;   // h*NL+i
    const float* p = part + (size_t)idx * 40;
    float D_ = 0.f;
    float A[8] = {};
    #pragma unroll
    for (int ck = 0; ck < 4; ++ck) {
        const float* q = p + ck * 10;
        D_ += q[0];
        #pragma unroll
        for (int d = 0; d < 8; ++d) A[d] += q[1 + d];
    }
    float inv = 1.f / D_;
    #pragma unroll
    for (int d = 0; d < 8; ++d) wbuf[(size_t)idx * 8 + d] = A[d] * inv;
}

// ------------------------------------------------------------------
// zw[h][i][d] = sum_j z[h][i][j] * w[h][j][d]
// ------------------------------------------------------------------
__global__ void zw_mul(const float* __restrict__ z, const float* __restrict__ w,
                       float* __restrict__ zw)
{
    int idx = blockIdx.x * 256 + threadIdx.x;
    int h = idx >> 11;
    int rem = idx & 2047;
    int i = rem >> 3, d = rem & 7;
    const float* zr = z + ((size_t)h * NL + i) * NL;
    const float* wb = w + (size_t)h * NL * DH + d;
    float s = 0.f;
    for (int j = 0; j < NL; ++j) s += zr[j] * wb[(size_t)j * DH];
    zw[idx] = s;
}

// ------------------------------------------------------------------
// attn1 fused + dwconv33(v): no-max softmax; 2 lanes/token; grid (154, 8)
// ------------------------------------------------------------------
__global__ void attn1_conv(const float* __restrict__ qh, const float* __restrict__ vh,
                           const float* __restrict__ klg, const float* __restrict__ zwg,
                           const float* __restrict__ rw, float* __restrict__ aout)
{
    const int h = blockIdx.y;
    __shared__ __align__(16) float kl[NL * DH];
    __shared__ __align__(16) float zw[NL * DH];
    const int tid = threadIdx.x;
    for (int q = tid; q < NL * DH; q += 256) {
        kl[q] = klg[(size_t)h * NL * DH + q];
        zw[q] = zwg[(size_t)h * NL * DH + q];
    }
    __syncthreads();
    const int half = tid & 1;
    const int r = blockIdx.x * 128 + (tid >> 1);
    if (r >= NT) return;
    const int t = r + PADR;
    const float* qp = qh + ((size_t)h * NP + t) * DH;
    float4 q0 = *(const float4*)qp;
    float4 q1 = *(const float4*)(qp + 4);
    float den = 0.f;
    float4 acc0 = make_float4(0.f, 0.f, 0.f, 0.f);
    float4 acc1 = make_float4(0.f, 0.f, 0.f, 0.f);
    const int iBeg = half * 128, iEnd = iBeg + 128;
    for (int i = iBeg; i < iEnd; ++i) {
        float4 k0 = *(const float4*)&kl[i * 8];
        float4 k1 = *(const float4*)&kl[i * 8 + 4];
        float s = q0.x * k0.x + q0.y * k0.y + q0.z * k0.z + q0.w * k0.w
                + q1.x * k1.x + q1.y * k1.y + q1.z * k1.z + q1.w * k1.w;
        float e = __expf(s);
        den += e;
        float4 z0 = *(const float4*)&zw[i * 8];
        float4 z1 = *(const float4*)&zw[i * 8 + 4];
        F4MAD(acc0, e, z0); F4MAD(acc1, e, z1);
    }
    // pair merge (lanes 2p / 2p+1 hold halves of the same token)
    {
        den += __shfl_xor(den, 1);
        float a[8] = {acc0.x, acc0.y, acc0.z, acc0.w, acc1.x, acc1.y, acc1.z, acc1.w};
        #pragma unroll
        for (int d = 0; d < 8; ++d) a[d] += __shfl_xor(a[d], 1);
        float inv = 1.f / den;
        acc0 = make_float4(a[0] * inv, a[1] * inv, a[2] * inv, a[3] * inv);
        acc1 = make_float4(a[4] * inv, a[5] * inv, a[6] * inv, a[7] * inv);
    }
    // conv: split taps between the two lanes
    const float* vb = vh + (size_t)h * NP * DH;
    float4 c0 = make_float4(0.f, 0.f, 0.f, 0.f);
    float4 c1 = make_float4(0.f, 0.f, 0.f, 0.f);
    for (int j = half; j < 33; j += 2) {
        int tp = t - 16 + j;
        if (tp >= NP) continue;
        float wv = rw[h * 33 + j];
        float4 v0 = *(const float4*)&vb[(size_t)tp * 8];
        float4 v1 = *(const float4*)&vb[(size_t)tp * 8 + 4];
        F4MAD(c0, wv, v0); F4MAD(c1, wv, v1);
    }
    c0.x += __shfl_xor(c0.x, 1); c0.y += __shfl_xor(c0.y, 1);
    c0.z += __shfl_xor(c0.z, 1); c0.w += __shfl_xor(c0.w, 1);
    c1.x += __shfl_xor(c1.x, 1); c1.y += __shfl_xor(c1.y, 1);
    c1.z += __shfl_xor(c1.z, 1); c1.w += __shfl_xor(c1.w, 1);
    if (half == 0) {
        float* op = aout + (size_t)r * 64 + h * 8;
        *(float4*)op = make_float4(acc0.x + c0.x, acc0.y + c0.y, acc0.z + c0.z, acc0.w + c0.w);
        *(float4*)(op + 4) = make_float4(acc1.x + c1.x, acc1.y + c1.y, acc1.z + c1.z, acc1.w + c1.w);
    }
}

// ------------------------------------------------------------------
// out-proj + residual: 16 rows/block
// ------------------------------------------------------------------
__global__ void outproj(const float* __restrict__ aout, const float* __restrict__ W,
                        const float* __restrict__ bias, float* __restrict__ h)
{
    const int r0 = blockIdx.x * 16;
    const int tid = threadIdx.x;   // 512
    __shared__ float ao[16][64];
    #pragma unroll
    for (int s = 0; s < 2; ++s) {
        int idx = tid + s * 512;
        int rr = idx >> 6, kk = idx & 63;
        int gr = r0 + rr;
        ao[rr][kk] = (gr < NT) ? aout[(size_t)gr * 64 + kk] : 0.f;
    }
    __syncthreads();
    float acc[16] = {};
    for (int k = 0; k < 64; ++k) {
        float wv = W[(size_t)k * HD + tid];
        #pragma unroll
        for (int r = 0; r < 16; ++r) acc[r] += ao[r][k] * wv;
    }
    float bv = bias[tid];
    #pragma unroll
    for (int r = 0; r < 16; ++r) {
        int gr = r0 + r;
        if (gr < NT) h[(size_t)gr * HD + tid] += acc[r] + bv;
    }
}

// ------------------------------------------------------------------
// PPEG
// ------------------------------------------------------------------
__global__ void ppeg_wprep(const float* __restrict__ w7, const float* __restrict__ b7,
                           const float* __restrict__ w5, const float* __restrict__ b5,
                           const float* __restrict__ w3, const float* __restrict__ b3,
                           float* __restrict__ wc, float* __restrict__ bsum)
{
    int idx = blockIdx.x * 256 + threadIdx.x;
    if (idx < HD * 49) {
        int c = idx / 49, t = idx - c * 49;
        int dy = t / 7 - 3, dx = t % 7 - 3;
        float v = w7[idx];
        if (dy >= -2 && dy <= 2 && dx >= -2 && dx <= 2) v += w5[c * 25 + (dy + 2) * 5 + (dx + 2)];
        if (dy >= -1 && dy <= 1 && dx >= -1 && dx <= 1) v += w3[c * 9 + (dy + 1) * 3 + (dx + 1)];
        if (t == 24) v += 1.f;
        wc[idx] = v;
    } else if (idx < HD * 49 + HD) {
        int c = idx - HD * 49;
        bsum[c] = b7[c] + b5[c] + b3[c];
    }
}

__global__ void ppeg_t1(const float* __restrict__ hin, float* __restrict__ plan, int ch0)
{
    __shared__ float tile[32][33];
    const int tx = threadIdx.x & 31, ty = threadIdx.x >> 5;
    const int p0 = blockIdx.x * 32;
    const int c0 = ch0 + blockIdx.y * 32;
    #pragma unroll
    for (int j = 0; j < 4; ++j) {
        int p = p0 + ty + j * 8;
        tile[ty + j * 8][tx] = (p < NPIX) ? hin[(size_t)(1 + p) * HD + c0 + tx] : 0.f;
    }
    __syncthreads();
    #pragma unroll
    for (int j = 0; j < 4; ++j) {
        int p = p0 + tx;
        int cc = ty + j * 8;
        if (p < NPIX) plan[(size_t)(blockIdx.y * 32 + cc) * NPIX + p] = tile[tx][cc];
    }
}

__global__ __launch_bounds__(256) void ppeg_conv(const float* __restrict__ plan,
                                                 const float* __restrict__ wc,
                                                 float* __restrict__ plan2, int ch0)
{
    __shared__ __align__(16) float img[41 * PW];
    const int tid = threadIdx.x;
    const int cl = blockIdx.x;
    const int yq = blockIdx.y;
    for (int i = tid; i < 41 * PW; i += 256) img[i] = 0.f;
    __syncthreads();
    const float* src = plan + (size_t)cl * NPIX;
    for (int i = tid; i < 41 * SIDE; i += 256) {
        int ly = i / SIDE, x = i - ly * SIDE;
        int y = yq * 35 - 3 + ly;
        if (y >= 0 && y < SIDE) img[ly * PW + x + 3] = src[y * SIDE + x];
    }
    const float* w = wc + (size_t)(ch0 + cl) * 49;
    float wr[49];
    #pragma unroll
    for (int t = 0; t < 49; ++t) wr[t] = w[t];
    __syncthreads();
    float* dst = plan2 + (size_t)cl * NPIX;
    for (int g = tid; g < 35 * 35; g += 256) {
        int yl = g / 35, x0 = (g - yl * 35) * 4;
        float acc0 = 0.f, acc1 = 0.f, acc2 = 0.f, acc3 = 0.f;
        #pragma unroll
        for (int a = 0; a < 7; ++a) {
            const float* row = &img[(yl + a) * PW + x0];
            float4 A = *(const float4*)(row);
            float4 B = *(const float4*)(row + 4);
            float4 C = *(const float4*)(row + 8);
            float e0 = A.x, e1 = A.y, e2 = A.z, e3 = A.w;
            float e4 = B.x, e5 = B.y, e6 = B.z, e7 = B.w;
            float e8 = C.x, e9 = C.y;
            const float w0 = wr[a*7+0], w1 = wr[a*7+1], w2 = wr[a*7+2], w3v = wr[a*7+3];
            const float w4 = wr[a*7+4], w5v = wr[a*7+5], w6 = wr[a*7+6];
            acc0 += w0*e0 + w1*e1 + w2*e2 + w3v*e3 + w4*e4 + w5v*e5 + w6*e6;
            acc1 += w0*e1 + w1*e2 + w2*e3 + w3v*e4 + w4*e5 + w5v*e6 + w6*e7;
            acc2 += w0*e2 + w1*e3 + w2*e4 + w3v*e5 + w4*e6 + w5v*e7 + w6*e8;
            acc3 += w0*e3 + w1*e4 + w2*e5 + w3v*e6 + w4*e7 + w5v*e8 + w6*e9;
        }
        *(float4*)&dst[(yq * 35 + yl) * SIDE + x0] = make_float4(acc0, acc1, acc2, acc3);
    }
}

__global__ void ppeg_t2(const float* __restrict__ plan2, const float* __restrict__ bsum,
                        float* __restrict__ hout, int ch0)
{
    __shared__ float tile[32][33];
    const int tx = threadIdx.x & 31, ty = threadIdx.x >> 5;
    const int p0 = blockIdx.x * 32;
    #pragma unroll
    for (int j = 0; j < 4; ++j) {
        int p = p0 + tx;
        int cc = ty + j * 8;
        tile[tx][cc] = (p < NPIX) ? plan2[(size_t)(blockIdx.y * 32 + cc) * NPIX + p] : 0.f;
    }
    __syncthreads();
    const int c0 = ch0 + blockIdx.y * 32;
    float bv = bsum[c0 + tx];
    #pragma unroll
    for (int j = 0; j < 4; ++j) {
        int p = p0 + ty + j * 8;
        if (p < NPIX) hout[(size_t)(1 + p) * HD + c0 + tx] = tile[ty + j * 8][tx] + bv;
    }
}

// ------------------------------------------------------------------
// final layernorm of row 0
// ------------------------------------------------------------------
__global__ void final_ln(const float* __restrict__ h, const float* __restrict__ g,
                         const float* __restrict__ b, float* __restrict__ out)
{
    const int tid = threadIdx.x;
    float v0 = h[tid], v1 = h[tid + 256];
    __shared__ float red[256];
    red[tid] = v0 + v1;
    __syncthreads();
    for (int off = 128; off > 0; off >>= 1) {
        if (tid < off) red[tid] += red[tid + off];
        __syncthreads();
    }
    float mu = red[0] * (1.f / HD);
    __syncthreads();
    float d0 = v0 - mu, d1 = v1 - mu;
    red[tid] = d0 * d0 + d1 * d1;
    __syncthreads();
    for (int off = 128; off > 0; off >>= 1) {
        if (tid < off) red[tid] += red[tid + off];
        __syncthreads();
    }
    float inv = rsqrtf(red[0] * (1.f / HD) + 1e-5f);
    out[tid]       = d0 * inv * g[tid] + b[tid];
    out[tid + 256] = d1 * inv * g[tid + 256] + b[tid + 256];
}

} // namespace

extern "C" void kernel_launch(void* const* d_in, const int* in_sizes, int n_in,
                              void* d_out, int out_size, void* d_ws, size_t ws_size,
                              hipStream_t stream)
{
    const float* x      = (const float*)d_in[0];
    const float* fc1_w  = (const float*)d_in[1];
    const float* fc1_b  = (const float*)d_in[2];
    const float* cls    = (const float*)d_in[3];
    const float* l1_g   = (const float*)d_in[4];
    const float* l1_bb  = (const float*)d_in[5];
    const float* l1_qkv = (const float*)d_in[6];
    const float* l1_ow  = (const float*)d_in[7];
    const float* l1_ob  = (const float*)d_in[8];
    const float* l1_rw  = (const float*)d_in[9];
    const float* l2_g   = (const float*)d_in[10];
    const float* l2_bb  = (const float*)d_in[11];
    const float* l2_qkv = (const float*)d_in[12];
    const float* l2_ow  = (const float*)d_in[13];
    const float* l2_ob  = (const float*)d_in[14];
    const float* l2_rw  = (const float*)d_in[15];
    const float* p7w    = (const float*)d_in[16];
    const float* p7b    = (const float*)d_in[17];
    const float* p5w    = (const float*)d_in[18];
    const float* p5b    = (const float*)d_in[19];
    const float* p3w    = (const float*)d_in[20];
    const float* p3b    = (const float*)d_in[21];
    const float* ng     = (const float*)d_in[22];
    const float* nb     = (const float*)d_in[23];
    float* out = (float*)d_out;

    char* ws = (char*)d_ws;
    size_t off = 0;
    auto alloc = [&](size_t bytes) {
        char* p = ws + off;
        off += (bytes + 255) & ~(size_t)255;
        return (void*)p;
    };
    float* bufA = (float*)alloc((size_t)NP * HD * 4);
    float* bufB = (float*)alloc((size_t)NP * HD * 4);
    float* qh   = (float*)alloc((size_t)NH * NP * DH * 4);
    float* kh   = (float*)alloc((size_t)NH * NP * DH * 4);
    float* vh   = (float*)alloc((size_t)NH * NP * DH * 4);
    float* aout = (float*)alloc((size_t)NP * 64 * 4);
    float* ql   = (float*)alloc((size_t)NH * NL * DH * 4);
    float* klm  = (float*)alloc((size_t)NH * NL * DH * 4);
    float* wbuf = (float*)alloc((size_t)NH * NL * DH * 4);
    float* zwb  = (float*)alloc((size_t)NH * NL * DH * 4);
    float* a2   = (float*)alloc((size_t)NH * NL * NL * 4);
    float* zb0  = (float*)alloc((size_t)NH * NL * NL * 4);
    float* zb1  = (float*)alloc((size_t)NH * NL * NL * 4);
    float* azb  = (float*)alloc((size_t)NH * NL * NL * 4);
    float* tb   = (float*)alloc((size_t)NH * NL * NL * 4);
    float* ub   = (float*)alloc((size_t)NH * NL * NL * 4);
    float* part = (float*)alloc(256);
    float* a3p  = (float*)alloc((size_t)NH * NL * 4 * 10 * 4);
    float* plan  = (float*)alloc((size_t)CCH * NPIX * 4);
    float* plan2 = (float*)alloc((size_t)CCH * NPIX * 4);
    float* wcomb = (float*)alloc((size_t)HD * 49 * 4);
    float* bsum  = (float*)alloc((size_t)HD * 4);
    short* wt1   = (short*)alloc((size_t)HD * ID * 2);
    short* wtq   = (short*)alloc((size_t)192 * HD * 2);
    short* xb    = (short*)alloc((size_t)NPIX * ID * 2);
    short* xpB   = (short*)alloc((size_t)NP * HD * 2);
    (void)ws_size; (void)in_sizes; (void)n_in; (void)out_size;

    castX<<<(NPIX * ID / 8) / 256, 256, 0, stream>>>(x, xb);
    castT<<<dim3(HD / 32, ID / 32), 256, 0, stream>>>(fc1_w, wt1, ID, HD);
    gemm_fc1<<<dim3(154, 8), 256, 0, stream>>>(xb, wt1, fc1_b, bufA);
    cls_init<<<2, 256, 0, stream>>>(cls, bufA);

    auto attention = [&](float* hbuf, const float* lg, const float* lb,
                         const float* qkvw, const float* ow, const float* ob,
                         const float* rw) {
        ln_pad<<<NP, 256, 0, stream>>>(hbuf, lg, lb, xpB);
        castT<<<dim3(192 / 32, HD / 32), 256, 0, stream>>>(qkvw, wtq, HD, 192);
        gemm_qkv<<<dim3(NP / 64, 3), 256, 0, stream>>>(xpB, wtq, qh, kh, vh);
        landmarks<<<128, 256, 0, stream>>>(qh, kh, ql, klm);
        attn2_softmax<<<dim3(NL, NH), 256, 0, stream>>>(ql, klm, a2);
        pinv_norms<<<16, 256, 0, stream>>>(a2, part);
        z0_init<<<2048, 256, 0, stream>>>(a2, part, zb0);
        float* zc = zb0;
        float* zn = zb1;
        for (int it = 0; it < 6; ++it) {
            mm256<<<dim3(8, 4, 8), 256, 0, stream>>>(a2, zc, azb, 1.f, 0.f);
            mm256<<<dim3(8, 4, 8), 256, 0, stream>>>(azb, azb, tb, -1.f, 7.f);
            mm256<<<dim3(8, 4, 8), 256, 0, stream>>>(azb, tb, ub, -1.f, 15.f);
            mm256<<<dim3(8, 4, 8), 256, 0, stream>>>(zc, ub, zn, -0.25f, 3.25f);
            float* tmp = zc; zc = zn; zn = tmp;
        }
        attn3v<<<dim3(NL / 4, NH, 4), 256, 0, stream>>>(kh, vh, ql, a3p);
        attn3v_merge<<<8, 256, 0, stream>>>(a3p, wbuf);
        zw_mul<<<64, 256, 0, stream>>>(zc, wbuf, zwb);
        attn1_conv<<<dim3(154, NH), 256, 0, stream>>>(qh, vh, klm, zwb, rw, aout);
        outproj<<<(NT + 15) / 16, 512, 0, stream>>>(aout, ow, ob, hbuf);
    };

    attention(bufA, l1_g, l1_bb, l1_qkv, l1_ow, l1_ob, l1_rw);

    ppeg_wprep<<<(HD * 49 + HD + 255) / 256, 256, 0, stream>>>(p7w, p7b, p5w, p5b, p3w, p3b,
                                                               wcomb, bsum);
    copy512<<<1, 512, 0, stream>>>(bufA, bufB);
    constexpr int PTILES = (NPIX + 31) / 32;
    for (int ch0 = 0; ch0 < HD; ch0 += CCH) {
        ppeg_t1<<<dim3(PTILES, CCH / 32), 256, 0, stream>>>(bufA, plan, ch0);
        ppeg_conv<<<dim3(CCH, 4), 256, 0, stream>>>(plan, wcomb, plan2, ch0);
        ppeg_t2<<<dim3(PTILES, CCH / 32), 256, 0, stream>>>(plan2, bsum, bufB, ch0);
    }

    attention(bufB, l2_g, l2_bb, l2_qkv, l2_ow, l2_ob, l2_rw);
    final_ln<<<1, 256, 0, stream>>>(bufB, ng, nb, out);
}